// Round 2
// baseline (2214.441 us; speedup 1.0000x reference)
//
#include <hip/hip_runtime.h>
#include <hip/hip_bf16.h>

typedef __hip_bfloat16 bf16;

#define BATCH 2
#define CH 64
#define NPIX 65536  // 256*256
#define HDIM 256
#define NLAYER 4
#define NGRP 8

// ---- workspace byte offsets (all f32 feat, bf16 q/kg/v) ----
#define OFS_FEAT   0ull
#define OFS_Q      33554432ull
#define OFS_KG     50331648ull
#define OFS_V      67108864ull
#define OFS_MEM    83886080ull
#define OFS_MFUSED 83918848ull
#define OFS_KNOW   83951616ull
#define OFS_FSUM   83984384ull
#define OFS_SSUM   83984896ull
#define OFS_STATS  83985024ull

__device__ __forceinline__ float b2f(bf16 v){ return __bfloat162float(v); }
__device__ __forceinline__ bf16  f2b(float v){ return __float2bfloat16(v); }
__device__ __forceinline__ float sigmoidf(float x){ return 1.0f/(1.0f+__expf(-x)); }
__device__ __forceinline__ float waveReduce(float v){
  #pragma unroll
  for (int off=32; off; off>>=1) v += __shfl_xor(v, off, 64);
  return v;
}

// ---------- per-block group-stat reduction helper ----------
__device__ __forceinline__ void blockStats(const float* gs, const float* gq,
                                           float* ssum_b, int t){
  __shared__ float sacc[16];
  if (t < 16) sacc[t] = 0.f;
  __syncthreads();
  #pragma unroll
  for (int g=0; g<NGRP; g++){
    float s  = waveReduce(gs[g]);
    float sq = waveReduce(gq[g]);
    if ((t & 63) == 0){ atomicAdd(&sacc[g*2], s); atomicAdd(&sacc[g*2+1], sq); }
  }
  __syncthreads();
  if (t < 16) atomicAdd(&ssum_b[t], sacc[t]);
}

// ---------- conv3x3 2->64 + fused GN stats ----------
__global__ void k_conv_in(const float* __restrict__ x, const float* __restrict__ w,
                          const float* __restrict__ bias,
                          float* __restrict__ feat, float* __restrict__ ssum){
  int b = blockIdx.y;
  int t = threadIdx.x;
  int n = blockIdx.x*256 + t;
  int y = n >> 8, xx = n & 255;
  float patch[18];
  int idx = 0;
  #pragma unroll
  for (int ci=0; ci<2; ci++)
    #pragma unroll
    for (int dy=-1; dy<=1; dy++)
      #pragma unroll
      for (int dx=-1; dx<=1; dx++){
        int yy = y+dy, xc = xx+dx;
        float v = 0.f;
        if (yy>=0 && yy<HDIM && xc>=0 && xc<HDIM)
          v = x[((b*2+ci)*HDIM + yy)*HDIM + xc];
        patch[idx++] = v;
      }
  float gs[NGRP], gq[NGRP];
  #pragma unroll
  for (int g=0; g<NGRP; g++){ gs[g]=0.f; gq[g]=0.f; }
  for (int o=0; o<CH; o++){
    float acc = bias[o];
    #pragma unroll
    for (int k=0; k<18; k++) acc += w[o*18+k]*patch[k];
    feat[(size_t)(b*CH+o)*NPIX + n] = acc;
    gs[o>>3] += acc; gq[o>>3] += acc*acc;
  }
  blockStats(gs, gq, ssum + b*16, t);
}

// ---------- finalize GN stats ----------
__global__ void k_finalize(const float* __restrict__ ssum, float* __restrict__ stats){
  int t = threadIdx.x;
  if (t >= BATCH*NGRP) return;
  int b = t >> 3, g = t & 7;
  const float inv = 1.0f/(8.0f*NPIX);
  float s  = ssum[b*16 + g*2];
  float sq = ssum[b*16 + g*2 + 1];
  float mu = s*inv;
  float var = sq*inv - mu*mu;
  stats[b*16 + g*2]     = mu;
  stats[b*16 + g*2 + 1] = rsqrtf(var + 1e-5f);
}

// ---------- GN-apply + q/k/v/gates 1x1 GEMMs ----------
__global__ void k_qkvg(const float* __restrict__ feat, const float* __restrict__ stats,
                       const float* __restrict__ gammaP, const float* __restrict__ betaP,
                       const float* __restrict__ WqP, const float* __restrict__ bqP,
                       const float* __restrict__ WkP, const float* __restrict__ bkP,
                       const float* __restrict__ WvP, const float* __restrict__ bvP,
                       const float* __restrict__ WgP, const float* __restrict__ bgP,
                       int l,
                       bf16* __restrict__ q, bf16* __restrict__ kg, bf16* __restrict__ v,
                       float* __restrict__ f_sum){
  int b = blockIdx.y;
  int t = threadIdx.x;
  int n = blockIdx.x*256 + t;
  float mu[NGRP], rstd[NGRP];
  #pragma unroll
  for (int g=0; g<NGRP; g++){ mu[g]=stats[b*16+g*2]; rstd[g]=stats[b*16+g*2+1]; }
  const float* gamma = gammaP + l*CH;
  const float* beta  = betaP  + l*CH;
  float xcol[CH];
  #pragma unroll
  for (int c=0; c<CH; c++){
    float fv = feat[(size_t)(b*CH+c)*NPIX + n];
    int g = c >> 3;
    xcol[c] = (fv - mu[g])*rstd[g]*gamma[c] + beta[c];
  }
  const float* Wq = WqP + l*4096; const float* bq = bqP + l*CH;
  const float* Wk = WkP + l*4096; const float* bk = bkP + l*CH;
  const float* Wv = WvP + l*4096; const float* bv = bvP + l*CH;
  const float* Wg = WgP + l*8192; const float* bg = bgP + l*2*CH;
  // q (scaled by C^-0.5)
  for (int o=0; o<CH; o++){
    float acc = 0.f;
    #pragma unroll
    for (int k=0; k<CH; k++) acc += Wq[o*CH+k]*xcol[k];
    q[(size_t)(b*CH+o)*NPIX + n] = f2b((acc + bq[o])*0.125f);
  }
  // v
  for (int o=0; o<CH; o++){
    float acc = bv[o];
    #pragma unroll
    for (int k=0; k<CH; k++) acc += Wv[o*CH+k]*xcol[k];
    v[(size_t)(b*CH+o)*NPIX + n] = f2b(acc);
  }
  // k gated by sigmoid(i)
  for (int c=0; c<CH; c++){
    float acck = bk[c];
    float acci = bg[CH + c];
    #pragma unroll
    for (int k=0; k<CH; k++){
      acck += Wk[c*CH+k]*xcol[k];
      acci += Wg[(CH+c)*CH+k]*xcol[k];
    }
    kg[(size_t)(b*CH+c)*NPIX + n] = f2b(acck * sigmoidf(acci));
  }
  // f gate mean accumulation
  __shared__ float facc[CH];
  if (t < CH) facc[t] = 0.f;
  __syncthreads();
  for (int c=0; c<CH; c++){
    float acc = bg[c];
    #pragma unroll
    for (int k=0; k<CH; k++) acc += Wg[c*CH+k]*xcol[k];
    float f = sigmoidf(acc);
    f = waveReduce(f);
    if ((t & 63) == 0) atomicAdd(&facc[c], f);
  }
  __syncthreads();
  if (t < CH) atomicAdd(&f_sum[b*CH + t], facc[t]);
}

// ---------- new_knowledge = sum_n kg[c,n]*v[d,n] ----------
#define KCHUNK 512
__global__ void k_knowledge(const bf16* __restrict__ kg, const bf16* __restrict__ v,
                            float* __restrict__ know){
  int b = blockIdx.y;
  int n0 = blockIdx.x * KCHUNK;
  int t = threadIdx.x;
  __shared__ float skT[64*69];
  __shared__ float svT[64*69];
  int cBase = (t >> 4) * 4;
  int dBase = (t & 15) * 4;
  float acc[4][4];
  #pragma unroll
  for (int i=0;i<4;i++)
    #pragma unroll
    for (int j=0;j<4;j++) acc[i][j]=0.f;
  for (int nt=0; nt<KCHUNK; nt+=64){
    __syncthreads();
    #pragma unroll
    for (int r=0; r<16; r++){
      int i = t + r*256;
      int c = i >> 6, nn = i & 63;
      size_t gidx = (size_t)(b*CH+c)*NPIX + n0 + nt + nn;
      skT[nn*69 + c] = b2f(kg[gidx]);
      svT[nn*69 + c] = b2f(v[gidx]);
    }
    __syncthreads();
    for (int nn=0; nn<64; nn++){
      float kk[4], vv[4];
      #pragma unroll
      for (int i=0;i<4;i++) kk[i] = skT[nn*69 + cBase + i];
      #pragma unroll
      for (int j=0;j<4;j++) vv[j] = svT[nn*69 + dBase + j];
      #pragma unroll
      for (int i=0;i<4;i++)
        #pragma unroll
        for (int j=0;j<4;j++) acc[i][j] += kk[i]*vv[j];
    }
  }
  #pragma unroll
  for (int i=0;i<4;i++)
    #pragma unroll
    for (int j=0;j<4;j++)
      atomicAdd(&know[(size_t)(b*CH + cBase+i)*CH + dBase + j], acc[i][j]);
}

// ---------- memory update ----------
__global__ void k_memupdate(const float* __restrict__ know, const float* __restrict__ f_sum,
                            const float* __restrict__ hidden_in, float* __restrict__ mem,
                            float* __restrict__ hidden_out, int l){
  int idx = blockIdx.x*256 + threadIdx.x;
  if (idx >= BATCH*CH*CH) return;
  int b = idx >> 12;
  int cd = idx & 4095;
  int c = cd >> 6;
  const float invN = 1.0f/(float)NPIX;
  float fmean = f_sum[b*CH + c] * invN;
  float kn = know[idx] * invN;
  float pm = hidden_in[(size_t)(b*NLAYER + l)*4096 + cd];
  float nm = fmean*pm + kn;
  mem[idx] = nm;
  hidden_out[(size_t)(b*NLAYER + l)*4096 + cd] = nm;
}

// ---------- Mfused[o][c] = sum_d Wp[o][d]*mem[c][d] ----------
__global__ void k_fusemem(const float* __restrict__ mem, const float* __restrict__ WpP, int l,
                          float* __restrict__ mfused){
  int b = blockIdx.y;
  int oc = blockIdx.x*256 + threadIdx.x;
  if (oc >= CH*CH) return;
  int o = oc >> 6, c = oc & 63;
  const float* Wp = WpP + l*4096;
  const float* mrow = mem + (size_t)b*4096 + c*CH;
  float acc = 0.f;
  #pragma unroll
  for (int d=0; d<CH; d++) acc += Wp[o*CH+d]*mrow[d];
  mfused[(size_t)b*4096 + oc] = acc;
}

// ---------- retrieval + projection + residual (in-place) + next-layer GN stats ----------
__global__ void k_retrproj(const bf16* __restrict__ q, const float* __restrict__ mfused,
                           const float* __restrict__ bpP, int l,
                           float* __restrict__ feat, float* __restrict__ ssum){
  int b = blockIdx.y;
  int t = threadIdx.x;
  int n = blockIdx.x*256 + t;
  __shared__ float smf[4096];
  for (int i=t; i<4096; i+=256) smf[i] = mfused[(size_t)b*4096 + i];
  __syncthreads();
  float qc[CH];
  #pragma unroll
  for (int c=0; c<CH; c++) qc[c] = b2f(q[(size_t)(b*CH+c)*NPIX + n]);
  const float* bp = bpP + l*CH;
  float gs[NGRP], gq[NGRP];
  #pragma unroll
  for (int g=0; g<NGRP; g++){ gs[g]=0.f; gq[g]=0.f; }
  for (int o=0; o<CH; o++){
    float acc = bp[o];
    #pragma unroll
    for (int c=0; c<CH; c++) acc += smf[o*CH + c]*qc[c];
    size_t fi = (size_t)(b*CH+o)*NPIX + n;
    float outv = acc + feat[fi];
    feat[fi] = outv;
    gs[o>>3] += outv; gq[o>>3] += outv*outv;
  }
  blockStats(gs, gq, ssum + b*16, t);
}

// ---------- conv3x3 64->2 + residual x -> f32 out ----------
__global__ void k_conv_out(const float* __restrict__ feat, const float* __restrict__ w,
                           const float* __restrict__ bias,
                           const float* __restrict__ xin, float* __restrict__ out){
  int b = blockIdx.z;
  int tx0 = blockIdx.x*16, ty0 = blockIdx.y*16;
  int t = threadIdx.x;
  int lx = t & 15, ly = t >> 4;
  int gx = tx0 + lx, gy = ty0 + ly;
  __shared__ float tile[18*18];
  float acc0 = bias[0], acc1 = bias[1];
  for (int c=0; c<CH; c++){
    __syncthreads();
    for (int i=t; i<324; i+=256){
      int lyy = i/18, lxx = i%18;
      int gyy = ty0 - 1 + lyy, gxx = tx0 - 1 + lxx;
      tile[i] = (gyy>=0 && gyy<HDIM && gxx>=0 && gxx<HDIM)
              ? feat[(size_t)(b*CH+c)*NPIX + gyy*HDIM + gxx] : 0.f;
    }
    __syncthreads();
    #pragma unroll
    for (int dy=0; dy<3; dy++)
      #pragma unroll
      for (int dx=0; dx<3; dx++){
        float vv = tile[(ly+dy)*18 + lx+dx];
        acc0 += w[(0*CH+c)*9 + dy*3 + dx]*vv;
        acc1 += w[(1*CH+c)*9 + dy*3 + dx]*vv;
      }
  }
  size_t p0 = (size_t)(b*2+0)*NPIX + gy*HDIM + gx;
  size_t p1 = (size_t)(b*2+1)*NPIX + gy*HDIM + gx;
  out[p0] = acc0 + xin[p0];
  out[p1] = acc1 + xin[p1];
}

extern "C" void kernel_launch(void* const* d_in, const int* in_sizes, int n_in,
                              void* d_out, int out_size, void* d_ws, size_t ws_size,
                              hipStream_t stream){
  char* ws = (char*)d_ws;
  float* feat  = (float*)(ws + OFS_FEAT);
  bf16*  qb    = (bf16*)(ws + OFS_Q);
  bf16*  kgb   = (bf16*)(ws + OFS_KG);
  bf16*  vb    = (bf16*)(ws + OFS_V);
  float* mem   = (float*)(ws + OFS_MEM);
  float* mfu   = (float*)(ws + OFS_MFUSED);
  float* know  = (float*)(ws + OFS_KNOW);
  float* fsum  = (float*)(ws + OFS_FSUM);
  float* ssum  = (float*)(ws + OFS_SSUM);
  float* stats = (float*)(ws + OFS_STATS);

  const float* x      = (const float*)d_in[0];
  const float* hidden = (const float*)d_in[1];
  const float* W_in   = (const float*)d_in[2];
  const float* b_in   = (const float*)d_in[3];
  const float* gamma  = (const float*)d_in[4];
  const float* beta   = (const float*)d_in[5];
  const float* Wq     = (const float*)d_in[6];
  const float* bq     = (const float*)d_in[7];
  const float* Wk     = (const float*)d_in[8];
  const float* bk     = (const float*)d_in[9];
  const float* Wv     = (const float*)d_in[10];
  const float* bv     = (const float*)d_in[11];
  const float* Wg     = (const float*)d_in[12];
  const float* bg     = (const float*)d_in[13];
  const float* Wp     = (const float*)d_in[14];
  const float* bp     = (const float*)d_in[15];
  const float* W_out  = (const float*)d_in[16];
  const float* b_out  = (const float*)d_in[17];

  float* out        = (float*)d_out;
  float* hidden_out = out + BATCH*2*NPIX;

  hipMemsetAsync(ssum, 0, 128, stream);
  k_conv_in<<<dim3(NPIX/256, BATCH), dim3(256), 0, stream>>>(x, W_in, b_in, feat, ssum);

  for (int l=0; l<NLAYER; l++){
    k_finalize<<<dim3(1), dim3(64), 0, stream>>>(ssum, stats);
    hipMemsetAsync(know, 0, 33280, stream);  // know (32768B) + fsum (512B), contiguous
    k_qkvg<<<dim3(NPIX/256, BATCH), dim3(256), 0, stream>>>(
        feat, stats, gamma, beta, Wq, bq, Wk, bk, Wv, bv, Wg, bg, l, qb, kgb, vb, fsum);
    k_knowledge<<<dim3(NPIX/KCHUNK, BATCH), dim3(256), 0, stream>>>(kgb, vb, know);
    k_memupdate<<<dim3(32), dim3(256), 0, stream>>>(know, fsum, hidden, mem, hidden_out, l);
    k_fusemem<<<dim3(16, BATCH), dim3(256), 0, stream>>>(mem, Wp, l, mfu);
    hipMemsetAsync(ssum, 0, 128, stream);
    k_retrproj<<<dim3(NPIX/256, BATCH), dim3(256), 0, stream>>>(qb, mfu, bp, l, feat, ssum);
  }

  k_conv_out<<<dim3(HDIM/16, HDIM/16, BATCH), dim3(256), 0, stream>>>(feat, W_out, b_out, x, out);
}

// Round 3
// 1195.961 us; speedup vs baseline: 1.8516x; 1.8516x over previous
//
#include <hip/hip_runtime.h>
#include <hip/hip_bf16.h>

typedef __hip_bfloat16 bf16;
typedef __attribute__((ext_vector_type(8))) short bf16x8;
typedef __attribute__((ext_vector_type(4))) float f32x4;

#define BATCH 2
#define CH 64
#define NPIX 65536  // 256*256
#define HDIM 256
#define NLAYER 4
#define NGRP 8

// ---- workspace byte offsets ----
#define OFS_FEAT   0ull
#define OFS_KNOW   33554432ull
#define OFS_FSUM   33587200ull
#define OFS_SSUM   33587712ull
#define OFS_STATS  33587840ull
#define OFS_MEFF   33587968ull
#define OFS_BEFF   33620736ull

__device__ __forceinline__ float sigmoidf_(float x){ return 1.0f/(1.0f+__expf(-x)); }

// f32 -> bf16 bits, round-to-nearest-even
__device__ __forceinline__ short f2bs(float x){
  unsigned u = __float_as_uint(x);
  u += 0x7fffu + ((u >> 16) & 1u);
  return (short)(u >> 16);
}

__device__ __forceinline__ float waveReduce(float v){
  #pragma unroll
  for (int off=32; off; off>>=1) v += __shfl_xor(v, off, 64);
  return v;
}

// A-fragment: 8 consecutive f32 -> bf16x8
__device__ __forceinline__ bf16x8 loadA(const float* __restrict__ p){
  bf16x8 a;
  #pragma unroll
  for (int j=0;j<8;j++) a[j] = f2bs(p[j]);
  return a;
}

// ---------- per-block group-stat reduction helper (conv_in) ----------
__device__ __forceinline__ void blockStats(const float* gs, const float* gq,
                                           float* ssum_b, int t){
  __shared__ float sacc[16];
  if (t < 16) sacc[t] = 0.f;
  __syncthreads();
  #pragma unroll
  for (int g=0; g<NGRP; g++){
    float s  = waveReduce(gs[g]);
    float sq = waveReduce(gq[g]);
    if ((t & 63) == 0){ atomicAdd(&sacc[g*2], s); atomicAdd(&sacc[g*2+1], sq); }
  }
  __syncthreads();
  if (t < 16) atomicAdd(&ssum_b[t], sacc[t]);
}

// ---------- conv3x3 2->64 + fused GN stats ----------
__global__ void k_conv_in(const float* __restrict__ x, const float* __restrict__ w,
                          const float* __restrict__ bias,
                          float* __restrict__ feat, float* __restrict__ ssum){
  int b = blockIdx.y;
  int t = threadIdx.x;
  int n = blockIdx.x*256 + t;
  int y = n >> 8, xx = n & 255;
  float patch[18];
  int idx = 0;
  #pragma unroll
  for (int ci=0; ci<2; ci++)
    #pragma unroll
    for (int dy=-1; dy<=1; dy++)
      #pragma unroll
      for (int dx=-1; dx<=1; dx++){
        int yy = y+dy, xc = xx+dx;
        float v = 0.f;
        if (yy>=0 && yy<HDIM && xc>=0 && xc<HDIM)
          v = x[((b*2+ci)*HDIM + yy)*HDIM + xc];
        patch[idx++] = v;
      }
  float gs[NGRP], gq[NGRP];
  #pragma unroll
  for (int g=0; g<NGRP; g++){ gs[g]=0.f; gq[g]=0.f; }
  for (int o=0; o<CH; o++){
    float acc = bias[o];
    #pragma unroll
    for (int k=0; k<18; k++) acc += w[o*18+k]*patch[k];
    feat[(size_t)(b*CH+o)*NPIX + n] = acc;
    gs[o>>3] += acc; gq[o>>3] += acc*acc;
  }
  blockStats(gs, gq, ssum + b*16, t);
}

// ---------- finalize GN stats ----------
__global__ void k_finalize(const float* __restrict__ ssum, float* __restrict__ stats){
  int t = threadIdx.x;
  if (t >= BATCH*NGRP) return;
  int b = t >> 3, g = t & 7;
  const float inv = 1.0f/(8.0f*NPIX);
  float s  = ssum[b*16 + g*2];
  float sq = ssum[b*16 + g*2 + 1];
  float mu = s*inv;
  float var = sq*inv - mu*mu;
  stats[b*16 + g*2]     = mu;
  stats[b*16 + g*2 + 1] = rsqrtf(var + 1e-5f);
}

// ---------- MFMA: GN + k/i/v/f GEMMs + fused knowledge outer product ----------
__global__ __launch_bounds__(256) void k_qkvg_know(
    const float* __restrict__ feat, const float* __restrict__ stats,
    const float* __restrict__ gammaP, const float* __restrict__ betaP,
    const float* __restrict__ WkP, const float* __restrict__ bkP,
    const float* __restrict__ WvP, const float* __restrict__ bvP,
    const float* __restrict__ WgP, const float* __restrict__ bgP,
    int l, float* __restrict__ know, float* __restrict__ f_sum)
{
  int b = blockIdx.y;
  int n0 = blockIdx.x * 128;
  int t = threadIdx.x;
  int w = t >> 6;          // wave 0..3
  int lane = t & 63;
  int m = lane & 15;       // A row-in-tile / B,C col
  int quad = lane >> 4;

  __shared__ float s_gnA[64], s_gnB[64];
  __shared__ short s_kg[64*136];
  __shared__ short s_v [64*136];

  if (t < 64){
    int g = t >> 3;
    float mu = stats[b*16 + g*2], rstd = stats[b*16 + g*2 + 1];
    float A = rstd * gammaP[l*64 + t];
    s_gnA[t] = A;
    s_gnB[t] = betaP[l*64 + t] - mu * A;
  }
  __syncthreads();

  // B-fragments: xn[c][px], c = kc*32 + quad*8 + j, px = n0 + nt*16 + m
  bf16x8 Bf[2][8];
  #pragma unroll
  for (int kc=0; kc<2; kc++){
    #pragma unroll
    for (int j=0; j<8; j++){
      int c = kc*32 + quad*8 + j;
      float A = s_gnA[c], Bc = s_gnB[c];
      const float* fr = feat + (size_t)(b*CH+c)*NPIX + n0 + m;
      #pragma unroll
      for (int nt=0; nt<8; nt++)
        Bf[kc][nt][j] = f2bs(fmaf(fr[nt*16], A, Bc));
    }
  }

  const float* Wk_l = WkP + l*4096;
  const float* Wv_l = WvP + l*4096;
  const float* Wg_l = WgP + l*8192;
  int rowbase = w*16;

  // ---- k & i tiles -> kg ----
  {
    bf16x8 Ak[2], Ai[2];
    #pragma unroll
    for (int kc=0;kc<2;kc++){
      Ak[kc] = loadA(Wk_l + (rowbase + m)*64 + kc*32 + quad*8);
      Ai[kc] = loadA(Wg_l + (64 + rowbase + m)*64 + kc*32 + quad*8);
    }
    float bkv[4], biv[4];
    #pragma unroll
    for (int r=0;r<4;r++){
      int row = rowbase + quad*4 + r;
      bkv[r] = bkP[l*64 + row];
      biv[r] = bgP[l*128 + 64 + row];
    }
    #pragma unroll
    for (int half=0; half<2; half++){
      f32x4 acck[4], acci[4];
      f32x4 z = {0.f,0.f,0.f,0.f};
      #pragma unroll
      for (int q4=0;q4<4;q4++){ acck[q4]=z; acci[q4]=z; }
      #pragma unroll
      for (int kc=0;kc<2;kc++)
        #pragma unroll
        for (int q4=0;q4<4;q4++){
          acck[q4] = __builtin_amdgcn_mfma_f32_16x16x32_bf16(Ak[kc], Bf[kc][half*4+q4], acck[q4], 0,0,0);
          acci[q4] = __builtin_amdgcn_mfma_f32_16x16x32_bf16(Ai[kc], Bf[kc][half*4+q4], acci[q4], 0,0,0);
        }
      #pragma unroll
      for (int q4=0;q4<4;q4++){
        int nt = half*4+q4;
        #pragma unroll
        for (int r=0;r<4;r++){
          int row = rowbase + quad*4 + r;
          float kv = acck[q4][r] + bkv[r];
          float iv = acci[q4][r] + biv[r];
          s_kg[row*136 + nt*16 + m] = f2bs(kv * sigmoidf_(iv));
        }
      }
    }
  }
  // ---- v tiles ----
  {
    bf16x8 Av[2];
    #pragma unroll
    for (int kc=0;kc<2;kc++)
      Av[kc] = loadA(Wv_l + (rowbase + m)*64 + kc*32 + quad*8);
    float bvv[4];
    #pragma unroll
    for (int r=0;r<4;r++) bvv[r] = bvP[l*64 + rowbase + quad*4 + r];
    #pragma unroll
    for (int half=0; half<2; half++){
      f32x4 accv[4];
      f32x4 z = {0.f,0.f,0.f,0.f};
      #pragma unroll
      for (int q4=0;q4<4;q4++) accv[q4]=z;
      #pragma unroll
      for (int kc=0;kc<2;kc++)
        #pragma unroll
        for (int q4=0;q4<4;q4++)
          accv[q4] = __builtin_amdgcn_mfma_f32_16x16x32_bf16(Av[kc], Bf[kc][half*4+q4], accv[q4], 0,0,0);
      #pragma unroll
      for (int q4=0;q4<4;q4++){
        int nt = half*4+q4;
        #pragma unroll
        for (int r=0;r<4;r++){
          int row = rowbase + quad*4 + r;
          s_v[row*136 + nt*16 + m] = f2bs(accv[q4][r] + bvv[r]);
        }
      }
    }
  }
  // ---- f tiles -> f_sum ----
  {
    bf16x8 Af[2];
    #pragma unroll
    for (int kc=0;kc<2;kc++)
      Af[kc] = loadA(Wg_l + (rowbase + m)*64 + kc*32 + quad*8);
    float bfv[4], fs[4];
    #pragma unroll
    for (int r=0;r<4;r++){ bfv[r] = bgP[l*128 + rowbase + quad*4 + r]; fs[r]=0.f; }
    #pragma unroll
    for (int half=0; half<2; half++){
      f32x4 accf[4];
      f32x4 z = {0.f,0.f,0.f,0.f};
      #pragma unroll
      for (int q4=0;q4<4;q4++) accf[q4]=z;
      #pragma unroll
      for (int kc=0;kc<2;kc++)
        #pragma unroll
        for (int q4=0;q4<4;q4++)
          accf[q4] = __builtin_amdgcn_mfma_f32_16x16x32_bf16(Af[kc], Bf[kc][half*4+q4], accf[q4], 0,0,0);
      #pragma unroll
      for (int q4=0;q4<4;q4++)
        #pragma unroll
        for (int r=0;r<4;r++)
          fs[r] += sigmoidf_(accf[q4][r] + bfv[r]);
    }
    #pragma unroll
    for (int off=1; off<16; off<<=1)
      #pragma unroll
      for (int r=0;r<4;r++) fs[r] += __shfl_xor(fs[r], off, 64);
    if (m == 0){
      #pragma unroll
      for (int r=0;r<4;r++)
        atomicAdd(&f_sum[b*64 + rowbase + quad*4 + r], fs[r]);
    }
  }
  __syncthreads();

  // ---- knowledge: know[c][d] += sum_px kg[c,px]*v[d,px], K=128 ----
  {
    f32x4 accn[4];
    f32x4 z = {0.f,0.f,0.f,0.f};
    #pragma unroll
    for (int dt=0;dt<4;dt++) accn[dt]=z;
    #pragma unroll
    for (int kc=0; kc<4; kc++){
      bf16x8 a = *(const bf16x8*)&s_kg[(rowbase + m)*136 + kc*32 + quad*8];
      #pragma unroll
      for (int dt=0; dt<4; dt++){
        bf16x8 bv = *(const bf16x8*)&s_v[(dt*16 + m)*136 + kc*32 + quad*8];
        accn[dt] = __builtin_amdgcn_mfma_f32_16x16x32_bf16(a, bv, accn[dt], 0,0,0);
      }
    }
    #pragma unroll
    for (int dt=0;dt<4;dt++)
      #pragma unroll
      for (int r=0;r<4;r++)
        atomicAdd(&know[(size_t)b*4096 + (rowbase + quad*4 + r)*64 + dt*16 + m], accn[dt][r]);
  }
}

// ---------- mem update + Meff = 0.125*Wp*mem^T*Wq, beff ----------
__global__ void k_memupd_meff(const float* __restrict__ know, const float* __restrict__ f_sum,
                              const float* __restrict__ hidden_in,
                              const float* __restrict__ WpP, const float* __restrict__ WqP,
                              const float* __restrict__ bqP, const float* __restrict__ bpP,
                              int l, float* __restrict__ hidden_out,
                              float* __restrict__ Meff, float* __restrict__ beff){
  int b = blockIdx.x;
  int t = threadIdx.x;
  __shared__ float s_memT[64*65];  // [d][c] = mem[c][d]
  __shared__ float s_mf[64*65];    // [o][c] = Mfused
  const float invN = 1.0f/(float)NPIX;
  #pragma unroll 1
  for (int i=0;i<16;i++){
    int cd = t + i*256;
    int c = cd >> 6, d = cd & 63;
    float fmean = f_sum[b*64 + c] * invN;
    float kn = know[b*4096 + cd] * invN;
    float pm = hidden_in[(size_t)(b*NLAYER+l)*4096 + cd];
    float nm = fmean*pm + kn;
    s_memT[d*65 + c] = nm;
    hidden_out[(size_t)(b*NLAYER+l)*4096 + cd] = nm;
  }
  __syncthreads();
  const float* Wp = WpP + l*4096;
  #pragma unroll 1
  for (int i=0;i<16;i++){
    int oc = t + i*256;
    int o = oc >> 6, c = oc & 63;
    float acc = 0.f;
    #pragma unroll
    for (int d=0; d<64; d++) acc += Wp[o*64+d] * s_memT[d*65 + c];
    s_mf[o*65 + c] = acc;
  }
  __syncthreads();
  const float* Wq = WqP + l*4096;
  #pragma unroll 1
  for (int i=0;i<16;i++){
    int oe = t + i*256;
    int o = oe >> 6, e = oe & 63;
    float acc = 0.f;
    #pragma unroll
    for (int c=0; c<64; c++) acc += s_mf[o*65+c] * Wq[c*64+e];
    Meff[(size_t)b*4096 + oe] = 0.125f * acc;
  }
  if (t < 64){
    float acc = 0.f;
    const float* bq = bqP + l*64;
    #pragma unroll
    for (int c=0;c<64;c++) acc += s_mf[t*65+c] * bq[c];
    beff[b*64 + t] = bpP[l*64 + t] + 0.125f*acc;
  }
}

// ---------- retrieval(+proj) = Meff * xn + beff + feat, + next-layer GN stats ----------
__global__ __launch_bounds__(256) void k_retrproj(
    const float* __restrict__ stats,
    const float* __restrict__ gammaP, const float* __restrict__ betaP,
    const float* __restrict__ Meff, const float* __restrict__ beff,
    int l, float* __restrict__ feat, float* __restrict__ ssum)
{
  int b = blockIdx.y;
  int n0 = blockIdx.x * 128;
  int t = threadIdx.x;
  int w = t >> 6;
  int lane = t & 63;
  int m = lane & 15;
  int quad = lane >> 4;

  __shared__ float s_gnA[64], s_gnB[64];
  if (t < 64){
    int g = t >> 3;
    float mu = stats[b*16 + g*2], rstd = stats[b*16 + g*2 + 1];
    float A = rstd * gammaP[l*64 + t];
    s_gnA[t] = A;
    s_gnB[t] = betaP[l*64 + t] - mu * A;
  }
  __syncthreads();

  bf16x8 Bf[2][8];
  #pragma unroll
  for (int kc=0; kc<2; kc++){
    #pragma unroll
    for (int j=0; j<8; j++){
      int c = kc*32 + quad*8 + j;
      float A = s_gnA[c], Bc = s_gnB[c];
      const float* fr = feat + (size_t)(b*CH+c)*NPIX + n0 + m;
      #pragma unroll
      for (int nt=0; nt<8; nt++)
        Bf[kc][nt][j] = f2bs(fmaf(fr[nt*16], A, Bc));
    }
  }
  __syncthreads();  // all frag reads of feat complete before any in-place writes

  bf16x8 Am[2];
  #pragma unroll
  for (int kc=0;kc<2;kc++)
    Am[kc] = loadA(Meff + (size_t)b*4096 + (w*16 + m)*64 + kc*32 + quad*8);

  f32x4 acc[8];
  f32x4 z = {0.f,0.f,0.f,0.f};
  #pragma unroll
  for (int nt=0;nt<8;nt++) acc[nt]=z;
  #pragma unroll
  for (int kc=0;kc<2;kc++)
    #pragma unroll
    for (int nt=0;nt<8;nt++)
      acc[nt] = __builtin_amdgcn_mfma_f32_16x16x32_bf16(Am[kc], Bf[kc][nt], acc[nt], 0,0,0);

  float bev[4];
  #pragma unroll
  for (int r=0;r<4;r++) bev[r] = beff[b*64 + w*16 + quad*4 + r];

  float gs = 0.f, gq = 0.f;
  #pragma unroll
  for (int nt=0;nt<8;nt++)
    #pragma unroll
    for (int r=0;r<4;r++){
      int row = w*16 + quad*4 + r;
      size_t fi = (size_t)(b*CH+row)*NPIX + n0 + nt*16 + m;
      float outv = acc[nt][r] + bev[r] + feat[fi];
      feat[fi] = outv;
      gs += outv; gq += outv*outv;
    }
  // lanes 0-31: group 2w, lanes 32-63: group 2w+1
  #pragma unroll
  for (int off=1; off<32; off<<=1){
    gs += __shfl_xor(gs, off, 64);
    gq += __shfl_xor(gq, off, 64);
  }
  if ((lane & 31) == 0){
    int g = 2*w + (quad >> 1);
    atomicAdd(&ssum[b*16 + g*2], gs);
    atomicAdd(&ssum[b*16 + g*2 + 1], gq);
  }
}

// ---------- conv3x3 64->2 + residual x -> f32 out ----------
__global__ void k_conv_out(const float* __restrict__ feat, const float* __restrict__ w,
                           const float* __restrict__ bias,
                           const float* __restrict__ xin, float* __restrict__ out){
  int b = blockIdx.z;
  int tx0 = blockIdx.x*16, ty0 = blockIdx.y*16;
  int t = threadIdx.x;
  int lx = t & 15, ly = t >> 4;
  int gx = tx0 + lx, gy = ty0 + ly;
  __shared__ float tile[18*18];
  float acc0 = bias[0], acc1 = bias[1];
  for (int c=0; c<CH; c++){
    __syncthreads();
    for (int i=t; i<324; i+=256){
      int lyy = i/18, lxx = i%18;
      int gyy = ty0 - 1 + lyy, gxx = tx0 - 1 + lxx;
      tile[i] = (gyy>=0 && gyy<HDIM && gxx>=0 && gxx<HDIM)
              ? feat[(size_t)(b*CH+c)*NPIX + gyy*HDIM + gxx] : 0.f;
    }
    __syncthreads();
    #pragma unroll
    for (int dy=0; dy<3; dy++)
      #pragma unroll
      for (int dx=0; dx<3; dx++){
        float vv = tile[(ly+dy)*18 + lx+dx];
        acc0 += w[(0*CH+c)*9 + dy*3 + dx]*vv;
        acc1 += w[(1*CH+c)*9 + dy*3 + dx]*vv;
      }
  }
  size_t p0 = (size_t)(b*2+0)*NPIX + gy*HDIM + gx;
  size_t p1 = (size_t)(b*2+1)*NPIX + gy*HDIM + gx;
  out[p0] = acc0 + xin[p0];
  out[p1] = acc1 + xin[p1];
}

extern "C" void kernel_launch(void* const* d_in, const int* in_sizes, int n_in,
                              void* d_out, int out_size, void* d_ws, size_t ws_size,
                              hipStream_t stream){
  char* ws = (char*)d_ws;
  float* feat  = (float*)(ws + OFS_FEAT);
  float* know  = (float*)(ws + OFS_KNOW);
  float* fsum  = (float*)(ws + OFS_FSUM);
  float* ssum  = (float*)(ws + OFS_SSUM);
  float* stats = (float*)(ws + OFS_STATS);
  float* meff  = (float*)(ws + OFS_MEFF);
  float* beff  = (float*)(ws + OFS_BEFF);

  const float* x      = (const float*)d_in[0];
  const float* hidden = (const float*)d_in[1];
  const float* W_in   = (const float*)d_in[2];
  const float* b_in   = (const float*)d_in[3];
  const float* gamma  = (const float*)d_in[4];
  const float* beta   = (const float*)d_in[5];
  const float* Wq     = (const float*)d_in[6];
  const float* bq     = (const float*)d_in[7];
  const float* Wk     = (const float*)d_in[8];
  const float* bk     = (const float*)d_in[9];
  const float* Wv     = (const float*)d_in[10];
  const float* bv     = (const float*)d_in[11];
  const float* Wg     = (const float*)d_in[12];
  const float* bg     = (const float*)d_in[13];
  const float* Wp     = (const float*)d_in[14];
  const float* bp     = (const float*)d_in[15];
  const float* W_out  = (const float*)d_in[16];
  const float* b_out  = (const float*)d_in[17];

  float* out        = (float*)d_out;
  float* hidden_out = out + BATCH*2*NPIX;

  hipMemsetAsync(ssum, 0, 128, stream);
  k_conv_in<<<dim3(NPIX/256, BATCH), dim3(256), 0, stream>>>(x, W_in, b_in, feat, ssum);

  for (int l=0; l<NLAYER; l++){
    k_finalize<<<dim3(1), dim3(64), 0, stream>>>(ssum, stats);
    hipMemsetAsync(know, 0, 33280, stream);  // know (32768B) + fsum (512B), contiguous
    k_qkvg_know<<<dim3(NPIX/128, BATCH), dim3(256), 0, stream>>>(
        feat, stats, gamma, beta, Wk, bk, Wv, bv, Wg, bg, l, know, fsum);
    k_memupd_meff<<<dim3(BATCH), dim3(256), 0, stream>>>(
        know, fsum, hidden, Wp, Wq, bq, bp, l, hidden_out, meff, beff);
    hipMemsetAsync(ssum, 0, 128, stream);
    k_retrproj<<<dim3(NPIX/128, BATCH), dim3(256), 0, stream>>>(
        stats, gamma, beta, meff, beff, l, feat, ssum);
  }

  k_conv_out<<<dim3(HDIM/16, HDIM/16, BATCH), dim3(256), 0, stream>>>(feat, W_out, b_out, x, out);
}

// Round 4
// 714.304 us; speedup vs baseline: 3.1001x; 1.6743x over previous
//
#include <hip/hip_runtime.h>
#include <hip/hip_bf16.h>

typedef __hip_bfloat16 bf16;
typedef __attribute__((ext_vector_type(8))) short bf16x8;
typedef __attribute__((ext_vector_type(4))) short short4v;
typedef __attribute__((ext_vector_type(4))) float f32x4;

#define BATCH 2
#define CH 64
#define NPIX 65536  // 256*256
#define HDIM 256
#define NLAYER 4
#define NGRP 8

// ---- workspace byte offsets ----
#define OFS_FEAT   0ull
#define OFS_KNOW   33554432ull   // 32768 B   (zeroed region start)
#define OFS_FSUM   33587200ull   // 512 B
#define OFS_SSUM   33587712ull   // 2 x 128 B (ping-pong)
#define OFS_BEFF   33587968ull   // 512 B
#define OFS_MEFFB  33588480ull   // 16384 B (bf16)
#define OFS_WKB    33604864ull   // 32768 B
#define OFS_WVB    33637632ull   // 32768 B
#define OFS_WGB    33670400ull   // 65536 B
#define ZERO_BYTES 33536         // know + fsum + ssum[2]

__device__ __forceinline__ float sigmoidf_(float x){ return 1.0f/(1.0f+__expf(-x)); }

// f32 -> bf16 bits, round-to-nearest-even
__device__ __forceinline__ short f2bs(float x){
  unsigned u = __float_as_uint(x);
  u += 0x7fffu + ((u >> 16) & 1u);
  return (short)(u >> 16);
}

__device__ __forceinline__ float waveReduce(float v){
  #pragma unroll
  for (int off=32; off; off>>=1) v += __shfl_xor(v, off, 64);
  return v;
}

// ---------- weight pre-convert f32 -> bf16 ----------
__global__ void k_prepw(const float* __restrict__ Wk, const float* __restrict__ Wv,
                        const float* __restrict__ Wg,
                        short* __restrict__ Wkb, short* __restrict__ Wvb,
                        short* __restrict__ Wgb){
  int i = blockIdx.x*256 + threadIdx.x;
  if (i < 16384){ Wkb[i] = f2bs(Wk[i]); Wvb[i] = f2bs(Wv[i]); }
  if (i < 32768) Wgb[i] = f2bs(Wg[i]);
}

// ---------- per-block group-stat reduction helper (conv_in) ----------
__device__ __forceinline__ void blockStats(const float* gs, const float* gq,
                                           float* ssum_b, int t){
  __shared__ float sacc[16];
  if (t < 16) sacc[t] = 0.f;
  __syncthreads();
  #pragma unroll
  for (int g=0; g<NGRP; g++){
    float s  = waveReduce(gs[g]);
    float sq = waveReduce(gq[g]);
    if ((t & 63) == 0){ atomicAdd(&sacc[g*2], s); atomicAdd(&sacc[g*2+1], sq); }
  }
  __syncthreads();
  if (t < 16) atomicAdd(&ssum_b[t], sacc[t]);
}

// ---------- conv3x3 2->64 + fused GN stats ----------
__global__ void k_conv_in(const float* __restrict__ x, const float* __restrict__ w,
                          const float* __restrict__ bias,
                          float* __restrict__ feat, float* __restrict__ ssum){
  int b = blockIdx.y;
  int t = threadIdx.x;
  int n = blockIdx.x*256 + t;
  int y = n >> 8, xx = n & 255;
  float patch[18];
  int idx = 0;
  #pragma unroll
  for (int ci=0; ci<2; ci++)
    #pragma unroll
    for (int dy=-1; dy<=1; dy++)
      #pragma unroll
      for (int dx=-1; dx<=1; dx++){
        int yy = y+dy, xc = xx+dx;
        float v = 0.f;
        if (yy>=0 && yy<HDIM && xc>=0 && xc<HDIM)
          v = x[((b*2+ci)*HDIM + yy)*HDIM + xc];
        patch[idx++] = v;
      }
  float gs[NGRP], gq[NGRP];
  #pragma unroll
  for (int g=0; g<NGRP; g++){ gs[g]=0.f; gq[g]=0.f; }
  for (int o=0; o<CH; o++){
    float acc = bias[o];
    #pragma unroll
    for (int k=0; k<18; k++) acc += w[o*18+k]*patch[k];
    feat[(size_t)(b*CH+o)*NPIX + n] = acc;
    gs[o>>3] += acc; gq[o>>3] += acc*acc;
  }
  blockStats(gs, gq, ssum + b*16, t);
}

// ---------- GN coefficient compute (inline per block) ----------
__device__ __forceinline__ void gnCoef(const float* __restrict__ ssum_l, int b, int t,
                                       const float* __restrict__ gammaP,
                                       const float* __restrict__ betaP, int l,
                                       float* s_gnA, float* s_gnB){
  if (t < 64){
    int g = t >> 3;
    const float inv = 1.0f/(8.0f*NPIX);
    float s  = ssum_l[b*16 + g*2];
    float sq = ssum_l[b*16 + g*2 + 1];
    float mu = s*inv;
    float var = sq*inv - mu*mu;
    float rstd = rsqrtf(var + 1e-5f);
    float A = rstd * gammaP[l*64 + t];
    s_gnA[t] = A;
    s_gnB[t] = betaP[l*64 + t] - mu * A;
  }
}

// ---------- MFMA: GN + k/i/v/f GEMMs + fused knowledge outer product ----------
// 2 pixel-tiles of 128 per block; knowledge accumulated in regs, atomics once.
__global__ __launch_bounds__(256) void k_qkvg_know(
    const float* __restrict__ feat, const float* __restrict__ ssum_l,
    const float* __restrict__ gammaP, const float* __restrict__ betaP,
    const short* __restrict__ Wkb, const float* __restrict__ bkP,
    const short* __restrict__ Wvb, const float* __restrict__ bvP,
    const short* __restrict__ Wgb, const float* __restrict__ bgP,
    int l, float* __restrict__ know, float* __restrict__ f_sum)
{
  int b = blockIdx.y;
  int n_base = blockIdx.x * 256;
  int t = threadIdx.x;
  int w = t >> 6;
  int lane = t & 63;
  int m = lane & 15;
  int quad = lane >> 4;
  int rowbase = w*16;

  __shared__ float s_gnA[64], s_gnB[64];
  __shared__ short s_xn[128*72];   // [px][c], row stride 72 shorts (144B = 9*16)
  __shared__ short s_kg[64*136];   // [c][px]
  __shared__ short s_v [64*136];

  gnCoef(ssum_l, b, t, gammaP, betaP, l, s_gnA, s_gnB);

  float bkv[4], biv[4], bvv[4], bfv[4], fs[4];
  #pragma unroll
  for (int r=0;r<4;r++){
    int row = rowbase + quad*4 + r;
    bkv[r] = bkP[l*64 + row];
    biv[r] = bgP[l*128 + 64 + row];
    bvv[r] = bvP[l*64 + row];
    bfv[r] = bgP[l*128 + row];
    fs[r] = 0.f;
  }
  f32x4 accn[4];
  f32x4 z4 = {0.f,0.f,0.f,0.f};
  #pragma unroll
  for (int dt=0;dt<4;dt++) accn[dt] = z4;

  __syncthreads();

  for (int tile=0; tile<2; tile++){
    if (tile) __syncthreads();   // protect LDS reuse across tiles
    int n0 = n_base + tile*128;
    // ---- stage GN'd tile: each element loaded/converted exactly once ----
    #pragma unroll
    for (int i=0;i<8;i++){
      int linear = t + i*256;
      int px = linear & 127;
      int c0 = (linear >> 7) * 4;
      short4v xnv;
      #pragma unroll
      for (int j=0;j<4;j++){
        float raw = feat[(size_t)(b*CH + c0 + j)*NPIX + n0 + px];
        xnv[j] = f2bs(fmaf(raw, s_gnA[c0+j], s_gnB[c0+j]));
      }
      *(short4v*)&s_xn[px*72 + c0] = xnv;
    }
    __syncthreads();
    // ---- B-fragments from LDS: 16 ds_read_b128 ----
    bf16x8 Bf[2][8];
    #pragma unroll
    for (int kc=0;kc<2;kc++)
      #pragma unroll
      for (int nt=0;nt<8;nt++)
        Bf[kc][nt] = *(const bf16x8*)&s_xn[(nt*16+m)*72 + kc*32 + quad*8];

    // ---- k & i -> kg ----
    {
      bf16x8 Ak[2], Ai[2];
      #pragma unroll
      for (int kc=0;kc<2;kc++){
        Ak[kc] = *(const bf16x8*)&Wkb[l*4096 + (rowbase+m)*64 + kc*32 + quad*8];
        Ai[kc] = *(const bf16x8*)&Wgb[l*8192 + (64+rowbase+m)*64 + kc*32 + quad*8];
      }
      #pragma unroll
      for (int half=0; half<2; half++){
        f32x4 acck[4], acci[4];
        #pragma unroll
        for (int q4=0;q4<4;q4++){ acck[q4]=z4; acci[q4]=z4; }
        #pragma unroll
        for (int kc=0;kc<2;kc++)
          #pragma unroll
          for (int q4=0;q4<4;q4++){
            acck[q4] = __builtin_amdgcn_mfma_f32_16x16x32_bf16(Ak[kc], Bf[kc][half*4+q4], acck[q4], 0,0,0);
            acci[q4] = __builtin_amdgcn_mfma_f32_16x16x32_bf16(Ai[kc], Bf[kc][half*4+q4], acci[q4], 0,0,0);
          }
        #pragma unroll
        for (int q4=0;q4<4;q4++){
          int nt = half*4+q4;
          #pragma unroll
          for (int r=0;r<4;r++){
            int row = rowbase + quad*4 + r;
            float kv = acck[q4][r] + bkv[r];
            float iv = acci[q4][r] + biv[r];
            s_kg[row*136 + nt*16 + m] = f2bs(kv * sigmoidf_(iv));
          }
        }
      }
    }
    // ---- v ----
    {
      bf16x8 Av[2];
      #pragma unroll
      for (int kc=0;kc<2;kc++)
        Av[kc] = *(const bf16x8*)&Wvb[l*4096 + (rowbase+m)*64 + kc*32 + quad*8];
      #pragma unroll
      for (int half=0; half<2; half++){
        f32x4 accv[4];
        #pragma unroll
        for (int q4=0;q4<4;q4++) accv[q4]=z4;
        #pragma unroll
        for (int kc=0;kc<2;kc++)
          #pragma unroll
          for (int q4=0;q4<4;q4++)
            accv[q4] = __builtin_amdgcn_mfma_f32_16x16x32_bf16(Av[kc], Bf[kc][half*4+q4], accv[q4], 0,0,0);
        #pragma unroll
        for (int q4=0;q4<4;q4++){
          int nt = half*4+q4;
          #pragma unroll
          for (int r=0;r<4;r++){
            int row = rowbase + quad*4 + r;
            s_v[row*136 + nt*16 + m] = f2bs(accv[q4][r] + bvv[r]);
          }
        }
      }
    }
    // ---- f -> fs ----
    {
      bf16x8 Af[2];
      #pragma unroll
      for (int kc=0;kc<2;kc++)
        Af[kc] = *(const bf16x8*)&Wgb[l*8192 + (rowbase+m)*64 + kc*32 + quad*8];
      #pragma unroll
      for (int half=0; half<2; half++){
        f32x4 accf[4];
        #pragma unroll
        for (int q4=0;q4<4;q4++) accf[q4]=z4;
        #pragma unroll
        for (int kc=0;kc<2;kc++)
          #pragma unroll
          for (int q4=0;q4<4;q4++)
            accf[q4] = __builtin_amdgcn_mfma_f32_16x16x32_bf16(Af[kc], Bf[kc][half*4+q4], accf[q4], 0,0,0);
        #pragma unroll
        for (int q4=0;q4<4;q4++)
          #pragma unroll
          for (int r=0;r<4;r++)
            fs[r] += sigmoidf_(accf[q4][r] + bfv[r]);
      }
    }
    __syncthreads();
    // ---- knowledge accumulate (regs) ----
    #pragma unroll
    for (int kc4=0; kc4<4; kc4++){
      bf16x8 a = *(const bf16x8*)&s_kg[(rowbase + m)*136 + kc4*32 + quad*8];
      #pragma unroll
      for (int dt=0; dt<4; dt++){
        bf16x8 bv8 = *(const bf16x8*)&s_v[(dt*16 + m)*136 + kc4*32 + quad*8];
        accn[dt] = __builtin_amdgcn_mfma_f32_16x16x32_bf16(a, bv8, accn[dt], 0,0,0);
      }
    }
  }

  // ---- f_sum: reduce over m-lanes, one atomic per (wave,row) ----
  #pragma unroll
  for (int off=1; off<16; off<<=1)
    #pragma unroll
    for (int r=0;r<4;r++) fs[r] += __shfl_xor(fs[r], off, 64);
  if (m == 0){
    #pragma unroll
    for (int r=0;r<4;r++)
      atomicAdd(&f_sum[b*64 + rowbase + quad*4 + r], fs[r]);
  }
  // ---- knowledge atomics (once per block) ----
  #pragma unroll
  for (int dt=0;dt<4;dt++)
    #pragma unroll
    for (int r=0;r<4;r++)
      atomicAdd(&know[(size_t)b*4096 + (rowbase + quad*4 + r)*64 + dt*16 + m], accn[dt][r]);
}

// ---------- mem update + Meff(bf16) + beff; zero buffers for next layer ----------
__global__ void k_memupd_meff(const float* __restrict__ know, float* __restrict__ f_sum,
                              const float* __restrict__ hidden_in,
                              const float* __restrict__ WpP, const float* __restrict__ WqP,
                              const float* __restrict__ bqP, const float* __restrict__ bpP,
                              int l, float* __restrict__ hidden_out,
                              short* __restrict__ Meffb, float* __restrict__ beff,
                              float* __restrict__ know_z, float* __restrict__ ssum_next){
  int b = blockIdx.x;
  int t = threadIdx.x;
  __shared__ float s_memT[64*65];  // [d][c]
  __shared__ float s_mf[64*65];    // [o][c]
  const float invN = 1.0f/(float)NPIX;
  #pragma unroll 1
  for (int i=0;i<16;i++){
    int cd = t + i*256;
    int c = cd >> 6, d = cd & 63;
    float fmean = f_sum[b*64 + c] * invN;
    float kn = know[b*4096 + cd] * invN;
    float pm = hidden_in[(size_t)(b*NLAYER+l)*4096 + cd];
    float nm = fmean*pm + kn;
    s_memT[d*65 + c] = nm;
    hidden_out[(size_t)(b*NLAYER+l)*4096 + cd] = nm;
  }
  __syncthreads();
  const float* Wp = WpP + l*4096;
  #pragma unroll 1
  for (int i=0;i<16;i++){
    int oc = t + i*256;
    int o = oc >> 6, c = oc & 63;
    float acc = 0.f;
    #pragma unroll
    for (int d=0; d<64; d++) acc += Wp[o*64+d] * s_memT[d*65 + c];
    s_mf[o*65 + c] = acc;
  }
  __syncthreads();
  const float* Wq = WqP + l*4096;
  #pragma unroll 1
  for (int i=0;i<16;i++){
    int oe = t + i*256;
    int o = oe >> 6, e = oe & 63;
    float acc = 0.f;
    #pragma unroll
    for (int c=0; c<64; c++) acc += s_mf[o*65+c] * Wq[c*64+e];
    Meffb[(size_t)b*4096 + oe] = f2bs(0.125f * acc);
  }
  if (t < 64){
    float acc = 0.f;
    const float* bq = bqP + l*64;
    #pragma unroll
    for (int c=0;c<64;c++) acc += s_mf[t*65+c] * bq[c];
    beff[b*64 + t] = bpP[l*64 + t] + 0.125f*acc;
  }
  // zero for next layer (reads above are complete for this block's range)
  #pragma unroll 1
  for (int i=0;i<16;i++) know_z[b*4096 + t + i*256] = 0.f;
  if (t < 64) f_sum[b*64 + t] = 0.f;
  if (t < 16) ssum_next[b*16 + t] = 0.f;
}

// ---------- retrieval+proj+residual in-place + next-layer GN stats ----------
__global__ __launch_bounds__(256) void k_retrproj(
    const float* __restrict__ ssum_l,
    const float* __restrict__ gammaP, const float* __restrict__ betaP,
    const short* __restrict__ Meffb, const float* __restrict__ beff,
    int l, float* __restrict__ feat, float* __restrict__ ssum_next)
{
  int b = blockIdx.y;
  int n0 = blockIdx.x * 128;
  int t = threadIdx.x;
  int w = t >> 6;
  int lane = t & 63;
  int m = lane & 15;
  int quad = lane >> 4;

  __shared__ float s_gnA[64], s_gnB[64];
  __shared__ float s_sacc[16];
  __shared__ short s_xn[128*72];
  __shared__ float s_raw[64*132];  // [c][px] raw feat, then +=(retr+beff)

  gnCoef(ssum_l, b, t, gammaP, betaP, l, s_gnA, s_gnB);
  if (t < 16) s_sacc[t] = 0.f;
  __syncthreads();

  // ---- stage: raw f32 + GN'd bf16 ----
  #pragma unroll
  for (int i=0;i<8;i++){
    int linear = t + i*256;
    int px = linear & 127;
    int c0 = (linear >> 7) * 4;
    short4v xnv;
    #pragma unroll
    for (int j=0;j<4;j++){
      float raw = feat[(size_t)(b*CH + c0 + j)*NPIX + n0 + px];
      s_raw[(c0+j)*132 + px] = raw;
      xnv[j] = f2bs(fmaf(raw, s_gnA[c0+j], s_gnB[c0+j]));
    }
    *(short4v*)&s_xn[px*72 + c0] = xnv;
  }
  __syncthreads();

  bf16x8 Bf[2][8];
  #pragma unroll
  for (int kc=0;kc<2;kc++)
    #pragma unroll
    for (int nt=0;nt<8;nt++)
      Bf[kc][nt] = *(const bf16x8*)&s_xn[(nt*16+m)*72 + kc*32 + quad*8];

  bf16x8 Am[2];
  #pragma unroll
  for (int kc=0;kc<2;kc++)
    Am[kc] = *(const bf16x8*)&Meffb[(size_t)b*4096 + (w*16 + m)*64 + kc*32 + quad*8];

  f32x4 acc[8];
  f32x4 z4 = {0.f,0.f,0.f,0.f};
  #pragma unroll
  for (int nt=0;nt<8;nt++) acc[nt]=z4;
  #pragma unroll
  for (int kc=0;kc<2;kc++)
    #pragma unroll
    for (int nt=0;nt<8;nt++)
      acc[nt] = __builtin_amdgcn_mfma_f32_16x16x32_bf16(Am[kc], Bf[kc][nt], acc[nt], 0,0,0);

  float bev[4];
  #pragma unroll
  for (int r=0;r<4;r++) bev[r] = beff[b*64 + w*16 + quad*4 + r];

  // accumulate retrieval+bias into s_raw (residual already there)
  #pragma unroll
  for (int nt=0;nt<8;nt++)
    #pragma unroll
    for (int r=0;r<4;r++){
      int row = w*16 + quad*4 + r;
      s_raw[row*132 + nt*16 + m] += acc[nt][r] + bev[r];
    }
  __syncthreads();

  // ---- coalesced writeback + next-layer GN stats ----
  #pragma unroll
  for (int i=0;i<8;i++){
    int linear = t + i*256;
    int px = linear & 127;
    int c0 = (linear >> 7) * 4;   // wave-uniform; group g = c0>>3 uniform
    float gsv = 0.f, gqv = 0.f;
    #pragma unroll
    for (int j=0;j<4;j++){
      float outv = s_raw[(c0+j)*132 + px];
      feat[(size_t)(b*CH + c0 + j)*NPIX + n0 + px] = outv;
      gsv += outv; gqv += outv*outv;
    }
    gsv = waveReduce(gsv);
    gqv = waveReduce(gqv);
    if (lane == 0){
      int g = c0 >> 3;
      atomicAdd(&s_sacc[g*2], gsv);
      atomicAdd(&s_sacc[g*2+1], gqv);
    }
  }
  __syncthreads();
  if (t < 16) atomicAdd(&ssum_next[b*16 + t], s_sacc[t]);
}

// ---------- conv3x3 64->2 + residual, 8-channel LDS chunks ----------
__global__ void k_conv_out(const float* __restrict__ feat, const float* __restrict__ w,
                           const float* __restrict__ bias,
                           const float* __restrict__ xin, float* __restrict__ out){
  int b = blockIdx.z;
  int tx0 = blockIdx.x*16, ty0 = blockIdx.y*16;
  int t = threadIdx.x;
  int lx = t & 15, ly = t >> 4;
  int gx = tx0 + lx, gy = ty0 + ly;
  __shared__ float tile[8*324];
  float acc0 = bias[0], acc1 = bias[1];
  for (int cc=0; cc<CH; cc+=8){
    __syncthreads();
    for (int i=t; i<2592; i+=256){
      int c = i/324, pos = i - c*324;
      int lyy = pos/18, lxx = pos - lyy*18;
      int gyy = ty0 - 1 + lyy, gxx = tx0 - 1 + lxx;
      tile[c*324 + pos] = (gyy>=0 && gyy<HDIM && gxx>=0 && gxx<HDIM)
              ? feat[(size_t)(b*CH+cc+c)*NPIX + gyy*HDIM + gxx] : 0.f;
    }
    __syncthreads();
    #pragma unroll
    for (int c=0;c<8;c++){
      #pragma unroll
      for (int dy=0; dy<3; dy++)
        #pragma unroll
        for (int dx=0; dx<3; dx++){
          float vv = tile[c*324 + (ly+dy)*18 + lx+dx];
          acc0 += w[(0*CH+cc+c)*9 + dy*3 + dx]*vv;
          acc1 += w[(1*CH+cc+c)*9 + dy*3 + dx]*vv;
        }
    }
  }
  size_t p0 = (size_t)(b*2+0)*NPIX + gy*HDIM + gx;
  size_t p1 = (size_t)(b*2+1)*NPIX + gy*HDIM + gx;
  out[p0] = acc0 + xin[p0];
  out[p1] = acc1 + xin[p1];
}

extern "C" void kernel_launch(void* const* d_in, const int* in_sizes, int n_in,
                              void* d_out, int out_size, void* d_ws, size_t ws_size,
                              hipStream_t stream){
  char* ws = (char*)d_ws;
  float* feat  = (float*)(ws + OFS_FEAT);
  float* know  = (float*)(ws + OFS_KNOW);
  float* fsum  = (float*)(ws + OFS_FSUM);
  float* ssum  = (float*)(ws + OFS_SSUM);   // 2 buffers of 32 floats
  float* beff  = (float*)(ws + OFS_BEFF);
  short* meffb = (short*)(ws + OFS_MEFFB);
  short* wkb   = (short*)(ws + OFS_WKB);
  short* wvb   = (short*)(ws + OFS_WVB);
  short* wgb   = (short*)(ws + OFS_WGB);

  const float* x      = (const float*)d_in[0];
  const float* hidden = (const float*)d_in[1];
  const float* W_in   = (const float*)d_in[2];
  const float* b_in   = (const float*)d_in[3];
  const float* gamma  = (const float*)d_in[4];
  const float* beta   = (const float*)d_in[5];
  const float* Wq     = (const float*)d_in[6];
  const float* bq     = (const float*)d_in[7];
  const float* Wk     = (const float*)d_in[8];
  const float* bk     = (const float*)d_in[9];
  const float* Wv     = (const float*)d_in[10];
  const float* bv     = (const float*)d_in[11];
  const float* Wg     = (const float*)d_in[12];
  const float* bg     = (const float*)d_in[13];
  const float* Wp     = (const float*)d_in[14];
  const float* bp     = (const float*)d_in[15];
  const float* W_out  = (const float*)d_in[16];
  const float* b_out  = (const float*)d_in[17];

  float* out        = (float*)d_out;
  float* hidden_out = out + BATCH*2*NPIX;

  hipMemsetAsync(ws + OFS_KNOW, 0, ZERO_BYTES, stream);
  k_prepw<<<dim3(128), dim3(256), 0, stream>>>(Wk, Wv, Wg, wkb, wvb, wgb);
  k_conv_in<<<dim3(NPIX/256, BATCH), dim3(256), 0, stream>>>(x, W_in, b_in, feat, ssum);

  for (int l=0; l<NLAYER; l++){
    float* ssum_l = ssum + (l & 1)*32;
    float* ssum_n = ssum + ((l+1) & 1)*32;
    k_qkvg_know<<<dim3(NPIX/256, BATCH), dim3(256), 0, stream>>>(
        feat, ssum_l, gamma, beta, wkb, bk, wvb, bv, wgb, bg, l, know, fsum);
    k_memupd_meff<<<dim3(BATCH), dim3(256), 0, stream>>>(
        know, fsum, hidden, Wp, Wq, bq, bp, l, hidden_out, meffb, beff, know, ssum_n);
    k_retrproj<<<dim3(NPIX/128, BATCH), dim3(256), 0, stream>>>(
        ssum_l, gamma, beta, meffb, beff, l, feat, ssum_n);
  }

  k_conv_out<<<dim3(HDIM/16, HDIM/16, BATCH), dim3(256), 0, stream>>>(feat, W_out, b_out, x, out);
}

// Round 5
// 556.818 us; speedup vs baseline: 3.9770x; 1.2828x over previous
//
#include <hip/hip_runtime.h>
#include <hip/hip_bf16.h>

typedef __hip_bfloat16 bf16;
typedef __attribute__((ext_vector_type(8))) short bf16x8;
typedef __attribute__((ext_vector_type(4))) short short4v;
typedef __attribute__((ext_vector_type(4))) float f32x4;

#define BATCH 2
#define CH 64
#define NPIX 65536  // 256*256
#define HDIM 256
#define NLAYER 4
#define NGRP 8

// ---- workspace byte offsets ----
// feat is [b][px][c] (c-minor) f32
#define OFS_FEAT   0ull
#define OFS_KNOW   33554432ull   // 4 reps x 2 b x 4096 f = 131072 B
#define OFS_FSUM   33685504ull   // 2 b x 64 entries x 32-f stride = 16384 B
#define OFS_SSUM   33701888ull   // 2 ping x (2 b x 16 entries x 32-f stride) = 16384 B
#define OFS_BEFF   33718272ull   // 512 B
#define OFS_MEFFB  33718784ull   // 16384 B (bf16)
#define OFS_WKB    33735168ull   // 32768 B
#define OFS_WVB    33767936ull   // 32768 B
#define OFS_WGB    33800704ull   // 65536 B
#define OFS_WTOUT  33866240ull   // 4608 B  ([o][k][c] f32)
#define ZERO_BYTES 163840        // know + fsum + ssum (contiguous from OFS_KNOW)

__device__ __forceinline__ float sigmoidf_(float x){ return 1.0f/(1.0f+__expf(-x)); }

// f32 -> bf16 bits, round-to-nearest-even
__device__ __forceinline__ short f2bs(float x){
  unsigned u = __float_as_uint(x);
  u += 0x7fffu + ((u >> 16) & 1u);
  return (short)(u >> 16);
}

__device__ __forceinline__ float waveReduce(float v){
  #pragma unroll
  for (int off=32; off; off>>=1) v += __shfl_xor(v, off, 64);
  return v;
}

// ---------- weight pre-convert: bf16 QKVG weights + transposed conv_out weights ----------
__global__ void k_prepw(const float* __restrict__ Wk, const float* __restrict__ Wv,
                        const float* __restrict__ Wg, const float* __restrict__ Wout,
                        short* __restrict__ Wkb, short* __restrict__ Wvb,
                        short* __restrict__ Wgb, float* __restrict__ wtout){
  int i = blockIdx.x*256 + threadIdx.x;
  if (i < 16384){ Wkb[i] = f2bs(Wk[i]); Wvb[i] = f2bs(Wv[i]); }
  if (i < 32768) Wgb[i] = f2bs(Wg[i]);
  if (i < 1152){
    int o = i / 576, rem = i % 576;
    int k = rem >> 6, c = rem & 63;
    wtout[(o*9 + k)*64 + c] = Wout[o*576 + c*9 + k];
  }
}

// ---------- per-block group-stat reduction (conv_in); ssum entries strided x32 ----------
__device__ __forceinline__ void blockStats(const float* gs, const float* gq,
                                           float* ssum_b, int t){
  __shared__ float sacc[16];
  if (t < 16) sacc[t] = 0.f;
  __syncthreads();
  #pragma unroll
  for (int g=0; g<NGRP; g++){
    float s  = waveReduce(gs[g]);
    float sq = waveReduce(gq[g]);
    if ((t & 63) == 0){ atomicAdd(&sacc[g*2], s); atomicAdd(&sacc[g*2+1], sq); }
  }
  __syncthreads();
  if (t < 16) atomicAdd(&ssum_b[t*32], sacc[t]);
}

// ---------- conv3x3 2->64 + fused GN stats; feat out [px][c] ----------
__global__ void k_conv_in(const float* __restrict__ x, const float* __restrict__ w,
                          const float* __restrict__ bias,
                          float* __restrict__ feat, float* __restrict__ ssum){
  int b = blockIdx.y;
  int t = threadIdx.x;
  int n = blockIdx.x*256 + t;
  int y = n >> 8, xx = n & 255;
  float patch[18];
  int idx = 0;
  #pragma unroll
  for (int ci=0; ci<2; ci++)
    #pragma unroll
    for (int dy=-1; dy<=1; dy++)
      #pragma unroll
      for (int dx=-1; dx<=1; dx++){
        int yy = y+dy, xc = xx+dx;
        float v = 0.f;
        if (yy>=0 && yy<HDIM && xc>=0 && xc<HDIM)
          v = x[((b*2+ci)*HDIM + yy)*HDIM + xc];
        patch[idx++] = v;
      }
  float gs[NGRP], gq[NGRP];
  #pragma unroll
  for (int g=0; g<NGRP; g++){ gs[g]=0.f; gq[g]=0.f; }
  float* fb = feat + ((size_t)b*NPIX + n)*64;
  #pragma unroll
  for (int c4=0; c4<16; c4++){
    f32x4 ov;
    #pragma unroll
    for (int j=0;j<4;j++){
      int o = c4*4 + j;
      float acc = bias[o];
      #pragma unroll
      for (int k=0; k<18; k++) acc += w[o*18+k]*patch[k];
      ov[j] = acc;
      gs[o>>3] += acc; gq[o>>3] += acc*acc;
    }
    *(f32x4*)(fb + c4*4) = ov;
  }
  blockStats(gs, gq, ssum + b*512, t);
}

// ---------- GN coefficient compute (ssum strided) ----------
__device__ __forceinline__ void gnCoef(const float* __restrict__ ssum_l, int b, int t,
                                       const float* __restrict__ gammaP,
                                       const float* __restrict__ betaP, int l,
                                       float* s_gnA, float* s_gnB){
  if (t < 64){
    int g = t >> 3;
    const float inv = 1.0f/(8.0f*NPIX);
    float s  = ssum_l[(b*16 + g*2)*32];
    float sq = ssum_l[(b*16 + g*2 + 1)*32];
    float mu = s*inv;
    float var = sq*inv - mu*mu;
    float rstd = rsqrtf(var + 1e-5f);
    float A = rstd * gammaP[l*64 + t];
    s_gnA[t] = A;
    s_gnB[t] = betaP[l*64 + t] - mu * A;
  }
}

// ---------- MFMA: GN + k/i/v/f GEMMs + fused knowledge; 128 px per block ----------
__global__ __launch_bounds__(256,3) void k_qkvg_know(
    const float* __restrict__ feat, const float* __restrict__ ssum_l,
    const float* __restrict__ gammaP, const float* __restrict__ betaP,
    const short* __restrict__ Wkb, const float* __restrict__ bkP,
    const short* __restrict__ Wvb, const float* __restrict__ bvP,
    const short* __restrict__ Wgb, const float* __restrict__ bgP,
    int l, float* __restrict__ know, float* __restrict__ f_sum)
{
  int b = blockIdx.y;
  int n0 = blockIdx.x * 128;
  int rep = blockIdx.x & 3;
  int t = threadIdx.x;
  int w = t >> 6;
  int lane = t & 63;
  int m = lane & 15;
  int quad = lane >> 4;
  int rowbase = w*16;

  __shared__ short s_buf[17408];        // 34816 B; s_kg+s_v, aliased by s_xn
  short* s_kg = s_buf;                   // [c][px] stride 136
  short* s_v  = s_buf + 8704;
  short* s_xn = s_buf;                   // [px][c] stride 72 (9216 shorts)
  __shared__ float s_gnA[64], s_gnB[64];

  gnCoef(ssum_l, b, t, gammaP, betaP, l, s_gnA, s_gnB);

  float bkv[4], biv[4], bvv[4], bfv[4], fs[4];
  #pragma unroll
  for (int r=0;r<4;r++){
    int row = rowbase + quad*4 + r;
    bkv[r] = bkP[l*64 + row];
    biv[r] = bgP[l*128 + 64 + row];
    bvv[r] = bvP[l*64 + row];
    bfv[r] = bgP[l*128 + row];
    fs[r] = 0.f;
  }
  f32x4 z4 = {0.f,0.f,0.f,0.f};
  f32x4 accn[4];
  #pragma unroll
  for (int dt=0;dt<4;dt++) accn[dt] = z4;

  __syncthreads();

  // ---- stage GN'd tile (vectorized) ----
  const float* fbase = feat + ((size_t)b*NPIX + n0)*64;
  #pragma unroll
  for (int i=0;i<8;i++){
    int chunk = t + i*256;
    int px = chunk >> 4, cq = chunk & 15;
    f32x4 fv = *(const f32x4*)(fbase + px*64 + cq*4);
    short4v xs;
    #pragma unroll
    for (int j=0;j<4;j++)
      xs[j] = f2bs(fmaf(fv[j], s_gnA[cq*4+j], s_gnB[cq*4+j]));
    *(short4v*)&s_xn[px*72 + cq*4] = xs;
  }
  __syncthreads();

  // ---- B-fragments ----
  bf16x8 Bf[2][8];
  #pragma unroll
  for (int kc=0;kc<2;kc++)
    #pragma unroll
    for (int nt=0;nt<8;nt++)
      Bf[kc][nt] = *(const bf16x8*)&s_xn[(nt*16+m)*72 + kc*32 + quad*8];
  __syncthreads();   // s_xn dead; s_kg/s_v writable

  // ---- k & i -> kg ----
  {
    bf16x8 Ak[2], Ai[2];
    #pragma unroll
    for (int kc=0;kc<2;kc++){
      Ak[kc] = *(const bf16x8*)&Wkb[l*4096 + (rowbase+m)*64 + kc*32 + quad*8];
      Ai[kc] = *(const bf16x8*)&Wgb[l*8192 + (64+rowbase+m)*64 + kc*32 + quad*8];
    }
    #pragma unroll
    for (int half=0; half<2; half++){
      f32x4 acck[4], acci[4];
      #pragma unroll
      for (int q4=0;q4<4;q4++){ acck[q4]=z4; acci[q4]=z4; }
      #pragma unroll
      for (int kc=0;kc<2;kc++)
        #pragma unroll
        for (int q4=0;q4<4;q4++){
          acck[q4] = __builtin_amdgcn_mfma_f32_16x16x32_bf16(Ak[kc], Bf[kc][half*4+q4], acck[q4], 0,0,0);
          acci[q4] = __builtin_amdgcn_mfma_f32_16x16x32_bf16(Ai[kc], Bf[kc][half*4+q4], acci[q4], 0,0,0);
        }
      #pragma unroll
      for (int q4=0;q4<4;q4++){
        int nt = half*4+q4;
        #pragma unroll
        for (int r=0;r<4;r++){
          int row = rowbase + quad*4 + r;
          float kv = acck[q4][r] + bkv[r];
          float iv = acci[q4][r] + biv[r];
          s_kg[row*136 + nt*16 + m] = f2bs(kv * sigmoidf_(iv));
        }
      }
    }
  }
  // ---- v ----
  {
    bf16x8 Av[2];
    #pragma unroll
    for (int kc=0;kc<2;kc++)
      Av[kc] = *(const bf16x8*)&Wvb[l*4096 + (rowbase+m)*64 + kc*32 + quad*8];
    #pragma unroll
    for (int half=0; half<2; half++){
      f32x4 accv[4];
      #pragma unroll
      for (int q4=0;q4<4;q4++) accv[q4]=z4;
      #pragma unroll
      for (int kc=0;kc<2;kc++)
        #pragma unroll
        for (int q4=0;q4<4;q4++)
          accv[q4] = __builtin_amdgcn_mfma_f32_16x16x32_bf16(Av[kc], Bf[kc][half*4+q4], accv[q4], 0,0,0);
      #pragma unroll
      for (int q4=0;q4<4;q4++){
        int nt = half*4+q4;
        #pragma unroll
        for (int r=0;r<4;r++){
          int row = rowbase + quad*4 + r;
          s_v[row*136 + nt*16 + m] = f2bs(accv[q4][r] + bvv[r]);
        }
      }
    }
  }
  // ---- f -> fs ----
  {
    bf16x8 Af[2];
    #pragma unroll
    for (int kc=0;kc<2;kc++)
      Af[kc] = *(const bf16x8*)&Wgb[l*8192 + (rowbase+m)*64 + kc*32 + quad*8];
    #pragma unroll
    for (int half=0; half<2; half++){
      f32x4 accf[4];
      #pragma unroll
      for (int q4=0;q4<4;q4++) accf[q4]=z4;
      #pragma unroll
      for (int kc=0;kc<2;kc++)
        #pragma unroll
        for (int q4=0;q4<4;q4++)
          accf[q4] = __builtin_amdgcn_mfma_f32_16x16x32_bf16(Af[kc], Bf[kc][half*4+q4], accf[q4], 0,0,0);
      #pragma unroll
      for (int q4=0;q4<4;q4++)
        #pragma unroll
        for (int r=0;r<4;r++)
          fs[r] += sigmoidf_(accf[q4][r] + bfv[r]);
    }
  }
  __syncthreads();

  // ---- knowledge ----
  #pragma unroll
  for (int kc4=0; kc4<4; kc4++){
    bf16x8 a = *(const bf16x8*)&s_kg[(rowbase + m)*136 + kc4*32 + quad*8];
    #pragma unroll
    for (int dt=0; dt<4; dt++){
      bf16x8 bv8 = *(const bf16x8*)&s_v[(dt*16 + m)*136 + kc4*32 + quad*8];
      accn[dt] = __builtin_amdgcn_mfma_f32_16x16x32_bf16(a, bv8, accn[dt], 0,0,0);
    }
  }

  // ---- f_sum (strided entries) ----
  #pragma unroll
  for (int off=1; off<16; off<<=1)
    #pragma unroll
    for (int r=0;r<4;r++) fs[r] += __shfl_xor(fs[r], off, 64);
  if (m == 0){
    #pragma unroll
    for (int r=0;r<4;r++)
      atomicAdd(&f_sum[(b*64 + rowbase + quad*4 + r)*32], fs[r]);
  }
  // ---- know atomics -> replica ----
  float* kr = know + (size_t)(rep*2 + b)*4096;
  #pragma unroll
  for (int dt=0;dt<4;dt++)
    #pragma unroll
    for (int r=0;r<4;r++)
      atomicAdd(&kr[(rowbase + quad*4 + r)*64 + dt*16 + m], accn[dt][r]);
}

// ---------- mem update + Meff(bf16) + beff; re-zero accumulators ----------
__global__ void k_memupd_meff(float* __restrict__ know, float* __restrict__ f_sum,
                              const float* __restrict__ hidden_in,
                              const float* __restrict__ WpP, const float* __restrict__ WqP,
                              const float* __restrict__ bqP, const float* __restrict__ bpP,
                              int l, float* __restrict__ hidden_out,
                              short* __restrict__ Meffb, float* __restrict__ beff,
                              float* __restrict__ ssum_next){
  int b = blockIdx.x;
  int t = threadIdx.x;
  __shared__ float s_memT[64*65];  // [d][c]
  __shared__ float s_mf[64*65];    // [o][c]
  const float invN = 1.0f/(float)NPIX;
  #pragma unroll 1
  for (int i=0;i<16;i++){
    int cd = t + i*256;
    int c = cd >> 6, d = cd & 63;
    float fmean = f_sum[(b*64 + c)*32] * invN;
    float kn = 0.f;
    #pragma unroll
    for (int rep=0; rep<4; rep++){
      kn += know[(size_t)(rep*2+b)*4096 + cd];
      know[(size_t)(rep*2+b)*4096 + cd] = 0.f;
    }
    kn *= invN;
    float pm = hidden_in[(size_t)(b*NLAYER+l)*4096 + cd];
    float nm = fmean*pm + kn;
    s_memT[d*65 + c] = nm;
    hidden_out[(size_t)(b*NLAYER+l)*4096 + cd] = nm;
  }
  __syncthreads();
  // safe to zero f_sum/ssum after sync (all reads done)
  if (t < 64) f_sum[(b*64 + t)*32] = 0.f;
  if (t < 16) ssum_next[(b*16 + t)*32] = 0.f;
  const float* Wp = WpP + l*4096;
  #pragma unroll 1
  for (int i=0;i<16;i++){
    int oc = t + i*256;
    int o = oc >> 6, c = oc & 63;
    float acc = 0.f;
    #pragma unroll
    for (int d=0; d<64; d++) acc += Wp[o*64+d] * s_memT[d*65 + c];
    s_mf[o*65 + c] = acc;
  }
  __syncthreads();
  const float* Wq = WqP + l*4096;
  #pragma unroll 1
  for (int i=0;i<16;i++){
    int oe = t + i*256;
    int o = oe >> 6, e = oe & 63;
    float acc = 0.f;
    #pragma unroll
    for (int c=0; c<64; c++) acc += s_mf[o*65+c] * Wq[c*64+e];
    Meffb[(size_t)b*4096 + oe] = f2bs(0.125f * acc);
  }
  if (t < 64){
    float acc = 0.f;
    const float* bq = bqP + l*64;
    #pragma unroll
    for (int c=0;c<64;c++) acc += s_mf[t*65+c] * bq[c];
    beff[b*64 + t] = bpP[l*64 + t] + 0.125f*acc;
  }
}

// ---------- retrieval+proj+residual in-place + next-layer GN stats ----------
__global__ __launch_bounds__(256,3) void k_retrproj(
    const float* __restrict__ ssum_l,
    const float* __restrict__ gammaP, const float* __restrict__ betaP,
    const short* __restrict__ Meffb, const float* __restrict__ beff,
    int l, float* __restrict__ feat, float* __restrict__ ssum_next)
{
  int b = blockIdx.y;
  int n0 = blockIdx.x * 128;
  int t = threadIdx.x;
  int w = t >> 6;
  int lane = t & 63;
  int m = lane & 15;
  int quad = lane >> 4;

  __shared__ float s_out[128*68];   // 34816 B; aliased by s_xn during staging
  short* s_xn = (short*)s_out;      // [px][c] stride 72 (18432 B)
  __shared__ float s_gnA[64], s_gnB[64], s_beff[64];
  __shared__ float s_sacc[16];

  gnCoef(ssum_l, b, t, gammaP, betaP, l, s_gnA, s_gnB);
  if (t < 64) s_beff[t] = beff[b*64 + t];
  if (t < 16) s_sacc[t] = 0.f;
  __syncthreads();

  const float* fbase = feat + ((size_t)b*NPIX + n0)*64;
  #pragma unroll
  for (int i=0;i<8;i++){
    int chunk = t + i*256;
    int px = chunk >> 4, cq = chunk & 15;
    f32x4 fv = *(const f32x4*)(fbase + px*64 + cq*4);
    short4v xs;
    #pragma unroll
    for (int j=0;j<4;j++)
      xs[j] = f2bs(fmaf(fv[j], s_gnA[cq*4+j], s_gnB[cq*4+j]));
    *(short4v*)&s_xn[px*72 + cq*4] = xs;
  }
  __syncthreads();

  bf16x8 Bf[2][8];
  #pragma unroll
  for (int kc=0;kc<2;kc++)
    #pragma unroll
    for (int nt=0;nt<8;nt++)
      Bf[kc][nt] = *(const bf16x8*)&s_xn[(nt*16+m)*72 + kc*32 + quad*8];

  bf16x8 Am[2];
  #pragma unroll
  for (int kc=0;kc<2;kc++)
    Am[kc] = *(const bf16x8*)&Meffb[(size_t)b*4096 + (w*16 + m)*64 + kc*32 + quad*8];
  __syncthreads();   // s_xn dead; s_out writable

  f32x4 acc[8];
  f32x4 z4 = {0.f,0.f,0.f,0.f};
  #pragma unroll
  for (int nt=0;nt<8;nt++) acc[nt]=z4;
  #pragma unroll
  for (int kc=0;kc<2;kc++)
    #pragma unroll
    for (int nt=0;nt<8;nt++)
      acc[nt] = __builtin_amdgcn_mfma_f32_16x16x32_bf16(Am[kc], Bf[kc][nt], acc[nt], 0,0,0);

  // transpose retrieval output into [px][c]
  #pragma unroll
  for (int nt=0;nt<8;nt++)
    #pragma unroll
    for (int r=0;r<4;r++)
      s_out[(nt*16+m)*68 + w*16 + quad*4 + r] = acc[nt][r];
  __syncthreads();

  // writeback (feat re-read is L1-hot) + next-layer GN stats
  float gsv = 0.f, gqv = 0.f;
  int cq = t & 15;
  #pragma unroll
  for (int i=0;i<8;i++){
    int chunk = t + i*256;
    int px = chunk >> 4;
    float* fp = (float*)(fbase + px*64 + cq*4);
    f32x4 fv = *(const f32x4*)fp;
    f32x4 ov = *(const f32x4*)&s_out[px*68 + cq*4];
    f32x4 res;
    #pragma unroll
    for (int j=0;j<4;j++){
      float o = fv[j] + ov[j] + s_beff[cq*4+j];
      res[j] = o;
      gsv += o; gqv += o*o;
    }
    *(f32x4*)fp = res;
  }
  // reduce the 8 lanes sharing a group (xor bits 0,4,5)
  gsv += __shfl_xor(gsv, 1, 64);  gqv += __shfl_xor(gqv, 1, 64);
  gsv += __shfl_xor(gsv, 16, 64); gqv += __shfl_xor(gqv, 16, 64);
  gsv += __shfl_xor(gsv, 32, 64); gqv += __shfl_xor(gqv, 32, 64);
  if ((lane & 49) == 0){
    int g = (lane & 15) >> 1;
    atomicAdd(&s_sacc[g*2], gsv);
    atomicAdd(&s_sacc[g*2+1], gqv);
  }
  __syncthreads();
  if (t < 16) atomicAdd(&ssum_next[(b*16 + t)*32], s_sacc[t]);
}

// ---------- conv3x3 64->2 + residual; feat [px][c], weights [o][k][c] ----------
__global__ void k_conv_out(const float* __restrict__ feat, const float* __restrict__ wt,
                           const float* __restrict__ bias,
                           const float* __restrict__ xin, float* __restrict__ out){
  int b = blockIdx.y;
  int y = blockIdx.x;
  int xx = threadIdx.x;
  float acc0 = bias[0], acc1 = bias[1];
  #pragma unroll
  for (int dy=-1; dy<=1; dy++){
    int yy = y + dy;
    if (yy < 0 || yy >= HDIM) continue;
    #pragma unroll
    for (int dx=-1; dx<=1; dx++){
      int xc = xx + dx;
      if (xc >= 0 && xc < HDIM){
        const float* fp = feat + ((size_t)b*NPIX + yy*HDIM + xc)*64;
        const float* w0 = wt + ((0*3 + dy+1)*3 + dx+1)*64;
        const float* w1 = wt + ((1*3 + dy+1)*3 + dx+1)*64;
        #pragma unroll
        for (int c4=0;c4<16;c4++){
          f32x4 fv  = *(const f32x4*)(fp + c4*4);
          f32x4 wv0 = *(const f32x4*)(w0 + c4*4);
          f32x4 wv1 = *(const f32x4*)(w1 + c4*4);
          #pragma unroll
          for (int j=0;j<4;j++){
            acc0 += fv[j]*wv0[j];
            acc1 += fv[j]*wv1[j];
          }
        }
      }
    }
  }
  size_t p0 = (size_t)(b*2+0)*NPIX + y*HDIM + xx;
  size_t p1 = (size_t)(b*2+1)*NPIX + y*HDIM + xx;
  out[p0] = acc0 + xin[p0];
  out[p1] = acc1 + xin[p1];
}

extern "C" void kernel_launch(void* const* d_in, const int* in_sizes, int n_in,
                              void* d_out, int out_size, void* d_ws, size_t ws_size,
                              hipStream_t stream){
  char* ws = (char*)d_ws;
  float* feat  = (float*)(ws + OFS_FEAT);
  float* know  = (float*)(ws + OFS_KNOW);
  float* fsum  = (float*)(ws + OFS_FSUM);
  float* ssum  = (float*)(ws + OFS_SSUM);   // 2 ping buffers of 1024 floats
  float* beff  = (float*)(ws + OFS_BEFF);
  short* meffb = (short*)(ws + OFS_MEFFB);
  short* wkb   = (short*)(ws + OFS_WKB);
  short* wvb   = (short*)(ws + OFS_WVB);
  short* wgb   = (short*)(ws + OFS_WGB);
  float* wtout = (float*)(ws + OFS_WTOUT);

  const float* x      = (const float*)d_in[0];
  const float* hidden = (const float*)d_in[1];
  const float* W_in   = (const float*)d_in[2];
  const float* b_in   = (const float*)d_in[3];
  const float* gamma  = (const float*)d_in[4];
  const float* beta   = (const float*)d_in[5];
  const float* Wq     = (const float*)d_in[6];
  const float* bq     = (const float*)d_in[7];
  const float* Wk     = (const float*)d_in[8];
  const float* bk     = (const float*)d_in[9];
  const float* Wv     = (const float*)d_in[10];
  const float* bv     = (const float*)d_in[11];
  const float* Wg     = (const float*)d_in[12];
  const float* bg     = (const float*)d_in[13];
  const float* Wp     = (const float*)d_in[14];
  const float* bp     = (const float*)d_in[15];
  const float* W_out  = (const float*)d_in[16];
  const float* b_out  = (const float*)d_in[17];

  float* out        = (float*)d_out;
  float* hidden_out = out + BATCH*2*NPIX;

  hipMemsetAsync(ws + OFS_KNOW, 0, ZERO_BYTES, stream);
  k_prepw<<<dim3(128), dim3(256), 0, stream>>>(Wk, Wv, Wg, W_out, wkb, wvb, wgb, wtout);
  k_conv_in<<<dim3(HDIM, BATCH), dim3(256), 0, stream>>>(x, W_in, b_in, feat, ssum);

  for (int l=0; l<NLAYER; l++){
    float* ssum_l = ssum + (l & 1)*1024;
    float* ssum_n = ssum + ((l+1) & 1)*1024;
    k_qkvg_know<<<dim3(NPIX/128, BATCH), dim3(256), 0, stream>>>(
        feat, ssum_l, gamma, beta, wkb, bk, wvb, bv, wgb, bg, l, know, fsum);
    k_memupd_meff<<<dim3(BATCH), dim3(256), 0, stream>>>(
        know, fsum, hidden, Wp, Wq, bq, bp, l, hidden_out, meffb, beff, ssum_n);
    k_retrproj<<<dim3(NPIX/128, BATCH), dim3(256), 0, stream>>>(
        ssum_l, gamma, beta, meffb, beff, l, feat, ssum_n);
  }

  k_conv_out<<<dim3(HDIM, BATCH), dim3(256), 0, stream>>>(feat, wtout, b_out, x, out);
}

// Round 6
// 404.266 us; speedup vs baseline: 5.4777x; 1.3774x over previous
//
#include <hip/hip_runtime.h>
#include <hip/hip_bf16.h>

typedef __hip_bfloat16 bf16;
typedef __attribute__((ext_vector_type(8))) short bf16x8;
typedef __attribute__((ext_vector_type(4))) short short4v;
typedef __attribute__((ext_vector_type(4))) float f32x4;

#define BATCH 2
#define CH 64
#define NPIX 65536  // 256*256
#define HDIM 256
#define NLAYER 4
#define NGRP 8

// ---- workspace byte offsets ----
// feat is [b][px][c] (c-minor) f32
#define OFS_FEAT   0ull
#define OFS_KNOW   33554432ull   // 4 reps x 2 b x 4096 f = 131072 B
#define OFS_FSUM   33685504ull   // 2 b x 64 entries x 32-f stride = 16384 B
#define OFS_SSUM   33701888ull   // 2 ping x (2 b x 16 entries x 32-f stride) = 16384 B
#define OFS_BEFF   33718272ull   // 512 B
#define OFS_MEFFB  33718784ull   // 16384 B (bf16)
#define OFS_WKB    33735168ull   // 32768 B
#define OFS_WVB    33767936ull   // 32768 B
#define OFS_WGB    33800704ull   // 65536 B
#define OFS_WTOUT  33866240ull   // 4608 B  ([o][k][c] f32)
#define OFS_WPB    33870848ull   // 32768 B (bf16)
#define OFS_WQTB   33903616ull   // 32768 B (bf16, transposed [e][c])
#define ZERO_BYTES 163840        // know + fsum + ssum (contiguous from OFS_KNOW)

__device__ __forceinline__ float sigmoidf_(float x){ return 1.0f/(1.0f+__expf(-x)); }

// f32 -> bf16 bits, round-to-nearest-even
__device__ __forceinline__ short f2bs(float x){
  unsigned u = __float_as_uint(x);
  u += 0x7fffu + ((u >> 16) & 1u);
  return (short)(u >> 16);
}

__device__ __forceinline__ float waveReduce(float v){
  #pragma unroll
  for (int off=32; off; off>>=1) v += __shfl_xor(v, off, 64);
  return v;
}

// ---------- weight pre-convert ----------
__global__ void k_prepw(const float* __restrict__ Wk, const float* __restrict__ Wv,
                        const float* __restrict__ Wg, const float* __restrict__ Wout,
                        const float* __restrict__ Wp, const float* __restrict__ Wq,
                        short* __restrict__ Wkb, short* __restrict__ Wvb,
                        short* __restrict__ Wgb, float* __restrict__ wtout,
                        short* __restrict__ Wpb, short* __restrict__ Wqtb){
  int i = blockIdx.x*256 + threadIdx.x;
  if (i < 16384){
    Wkb[i] = f2bs(Wk[i]);
    Wvb[i] = f2bs(Wv[i]);
    Wpb[i] = f2bs(Wp[i]);
    int l = i >> 12, within = i & 4095;
    int e = within >> 6, c = within & 63;
    Wqtb[i] = f2bs(Wq[l*4096 + c*64 + e]);   // WqT[e][c] = Wq[c][e]
  }
  if (i < 32768) Wgb[i] = f2bs(Wg[i]);
  if (i < 1152){
    int o = i / 576, rem = i % 576;
    int k = rem >> 6, c = rem & 63;
    wtout[(o*9 + k)*64 + c] = Wout[o*576 + c*9 + k];
  }
}

// ---------- per-block group-stat reduction (conv_in); ssum entries strided x32 ----------
__device__ __forceinline__ void blockStats(const float* gs, const float* gq,
                                           float* ssum_b, int t){
  __shared__ float sacc[16];
  if (t < 16) sacc[t] = 0.f;
  __syncthreads();
  #pragma unroll
  for (int g=0; g<NGRP; g++){
    float s  = waveReduce(gs[g]);
    float sq = waveReduce(gq[g]);
    if ((t & 63) == 0){ atomicAdd(&sacc[g*2], s); atomicAdd(&sacc[g*2+1], sq); }
  }
  __syncthreads();
  if (t < 16) atomicAdd(&ssum_b[t*32], sacc[t]);
}

// ---------- conv3x3 2->64 + fused GN stats; feat out [px][c] ----------
__global__ void k_conv_in(const float* __restrict__ x, const float* __restrict__ w,
                          const float* __restrict__ bias,
                          float* __restrict__ feat, float* __restrict__ ssum){
  int b = blockIdx.y;
  int t = threadIdx.x;
  int n = blockIdx.x*256 + t;
  int y = n >> 8, xx = n & 255;
  float patch[18];
  int idx = 0;
  #pragma unroll
  for (int ci=0; ci<2; ci++)
    #pragma unroll
    for (int dy=-1; dy<=1; dy++)
      #pragma unroll
      for (int dx=-1; dx<=1; dx++){
        int yy = y+dy, xc = xx+dx;
        float v = 0.f;
        if (yy>=0 && yy<HDIM && xc>=0 && xc<HDIM)
          v = x[((b*2+ci)*HDIM + yy)*HDIM + xc];
        patch[idx++] = v;
      }
  float gs[NGRP], gq[NGRP];
  #pragma unroll
  for (int g=0; g<NGRP; g++){ gs[g]=0.f; gq[g]=0.f; }
  float* fb = feat + ((size_t)b*NPIX + n)*64;
  #pragma unroll
  for (int c4=0; c4<16; c4++){
    f32x4 ov;
    #pragma unroll
    for (int j=0;j<4;j++){
      int o = c4*4 + j;
      float acc = bias[o];
      #pragma unroll
      for (int k=0; k<18; k++) acc += w[o*18+k]*patch[k];
      ov[j] = acc;
      gs[o>>3] += acc; gq[o>>3] += acc*acc;
    }
    *(f32x4*)(fb + c4*4) = ov;
  }
  blockStats(gs, gq, ssum + b*512, t);
}

// ---------- GN coefficient compute (ssum strided) ----------
__device__ __forceinline__ void gnCoef(const float* __restrict__ ssum_l, int b, int t,
                                       const float* __restrict__ gammaP,
                                       const float* __restrict__ betaP, int l,
                                       float* s_gnA, float* s_gnB){
  if (t < 64){
    int g = t >> 3;
    const float inv = 1.0f/(8.0f*NPIX);
    float s  = ssum_l[(b*16 + g*2)*32];
    float sq = ssum_l[(b*16 + g*2 + 1)*32];
    float mu = s*inv;
    float var = sq*inv - mu*mu;
    float rstd = rsqrtf(var + 1e-5f);
    float A = rstd * gammaP[l*64 + t];
    s_gnA[t] = A;
    s_gnB[t] = betaP[l*64 + t] - mu * A;
  }
}

// ---------- MFMA: GN + k/i/v/f GEMMs + fused knowledge; 128 px per block ----------
__global__ __launch_bounds__(256,3) void k_qkvg_know(
    const float* __restrict__ feat, const float* __restrict__ ssum_l,
    const float* __restrict__ gammaP, const float* __restrict__ betaP,
    const short* __restrict__ Wkb, const float* __restrict__ bkP,
    const short* __restrict__ Wvb, const float* __restrict__ bvP,
    const short* __restrict__ Wgb, const float* __restrict__ bgP,
    int l, float* __restrict__ know, float* __restrict__ f_sum)
{
  int b = blockIdx.y;
  int n0 = blockIdx.x * 128;
  int rep = blockIdx.x & 3;
  int t = threadIdx.x;
  int w = t >> 6;
  int lane = t & 63;
  int m = lane & 15;
  int quad = lane >> 4;
  int rowbase = w*16;

  __shared__ short s_buf[17408];        // 34816 B; s_kg+s_v, aliased by s_xn
  short* s_kg = s_buf;                   // [c][px] stride 136
  short* s_v  = s_buf + 8704;
  short* s_xn = s_buf;                   // [px][c] stride 72 (9216 shorts)
  __shared__ float s_gnA[64], s_gnB[64];

  gnCoef(ssum_l, b, t, gammaP, betaP, l, s_gnA, s_gnB);

  float bkv[4], biv[4], bvv[4], bfv[4], fs[4];
  #pragma unroll
  for (int r=0;r<4;r++){
    int row = rowbase + quad*4 + r;
    bkv[r] = bkP[l*64 + row];
    biv[r] = bgP[l*128 + 64 + row];
    bvv[r] = bvP[l*64 + row];
    bfv[r] = bgP[l*128 + row];
    fs[r] = 0.f;
  }
  f32x4 z4 = {0.f,0.f,0.f,0.f};
  f32x4 accn[4];
  #pragma unroll
  for (int dt=0;dt<4;dt++) accn[dt] = z4;

  __syncthreads();

  // ---- stage GN'd tile (vectorized) ----
  const float* fbase = feat + ((size_t)b*NPIX + n0)*64;
  #pragma unroll
  for (int i=0;i<8;i++){
    int chunk = t + i*256;
    int px = chunk >> 4, cq = chunk & 15;
    f32x4 fv = *(const f32x4*)(fbase + px*64 + cq*4);
    short4v xs;
    #pragma unroll
    for (int j=0;j<4;j++)
      xs[j] = f2bs(fmaf(fv[j], s_gnA[cq*4+j], s_gnB[cq*4+j]));
    *(short4v*)&s_xn[px*72 + cq*4] = xs;
  }
  __syncthreads();

  // ---- B-fragments ----
  bf16x8 Bf[2][8];
  #pragma unroll
  for (int kc=0;kc<2;kc++)
    #pragma unroll
    for (int nt=0;nt<8;nt++)
      Bf[kc][nt] = *(const bf16x8*)&s_xn[(nt*16+m)*72 + kc*32 + quad*8];
  __syncthreads();   // s_xn dead; s_kg/s_v writable

  // ---- k & i -> kg ----
  {
    bf16x8 Ak[2], Ai[2];
    #pragma unroll
    for (int kc=0;kc<2;kc++){
      Ak[kc] = *(const bf16x8*)&Wkb[l*4096 + (rowbase+m)*64 + kc*32 + quad*8];
      Ai[kc] = *(const bf16x8*)&Wgb[l*8192 + (64+rowbase+m)*64 + kc*32 + quad*8];
    }
    #pragma unroll
    for (int half=0; half<2; half++){
      f32x4 acck[4], acci[4];
      #pragma unroll
      for (int q4=0;q4<4;q4++){ acck[q4]=z4; acci[q4]=z4; }
      #pragma unroll
      for (int kc=0;kc<2;kc++)
        #pragma unroll
        for (int q4=0;q4<4;q4++){
          acck[q4] = __builtin_amdgcn_mfma_f32_16x16x32_bf16(Ak[kc], Bf[kc][half*4+q4], acck[q4], 0,0,0);
          acci[q4] = __builtin_amdgcn_mfma_f32_16x16x32_bf16(Ai[kc], Bf[kc][half*4+q4], acci[q4], 0,0,0);
        }
      #pragma unroll
      for (int q4=0;q4<4;q4++){
        int nt = half*4+q4;
        #pragma unroll
        for (int r=0;r<4;r++){
          int row = rowbase + quad*4 + r;
          float kv = acck[q4][r] + bkv[r];
          float iv = acci[q4][r] + biv[r];
          s_kg[row*136 + nt*16 + m] = f2bs(kv * sigmoidf_(iv));
        }
      }
    }
  }
  // ---- v ----
  {
    bf16x8 Av[2];
    #pragma unroll
    for (int kc=0;kc<2;kc++)
      Av[kc] = *(const bf16x8*)&Wvb[l*4096 + (rowbase+m)*64 + kc*32 + quad*8];
    #pragma unroll
    for (int half=0; half<2; half++){
      f32x4 accv[4];
      #pragma unroll
      for (int q4=0;q4<4;q4++) accv[q4]=z4;
      #pragma unroll
      for (int kc=0;kc<2;kc++)
        #pragma unroll
        for (int q4=0;q4<4;q4++)
          accv[q4] = __builtin_amdgcn_mfma_f32_16x16x32_bf16(Av[kc], Bf[kc][half*4+q4], accv[q4], 0,0,0);
      #pragma unroll
      for (int q4=0;q4<4;q4++){
        int nt = half*4+q4;
        #pragma unroll
        for (int r=0;r<4;r++){
          int row = rowbase + quad*4 + r;
          s_v[row*136 + nt*16 + m] = f2bs(accv[q4][r] + bvv[r]);
        }
      }
    }
  }
  // ---- f -> fs ----
  {
    bf16x8 Af[2];
    #pragma unroll
    for (int kc=0;kc<2;kc++)
      Af[kc] = *(const bf16x8*)&Wgb[l*8192 + (rowbase+m)*64 + kc*32 + quad*8];
    #pragma unroll
    for (int half=0; half<2; half++){
      f32x4 accf[4];
      #pragma unroll
      for (int q4=0;q4<4;q4++) accf[q4]=z4;
      #pragma unroll
      for (int kc=0;kc<2;kc++)
        #pragma unroll
        for (int q4=0;q4<4;q4++)
          accf[q4] = __builtin_amdgcn_mfma_f32_16x16x32_bf16(Af[kc], Bf[kc][half*4+q4], accf[q4], 0,0,0);
      #pragma unroll
      for (int q4=0;q4<4;q4++)
        #pragma unroll
        for (int r=0;r<4;r++)
          fs[r] += sigmoidf_(accf[q4][r] + bfv[r]);
    }
  }
  __syncthreads();

  // ---- knowledge ----
  #pragma unroll
  for (int kc4=0; kc4<4; kc4++){
    bf16x8 a = *(const bf16x8*)&s_kg[(rowbase + m)*136 + kc4*32 + quad*8];
    #pragma unroll
    for (int dt=0; dt<4; dt++){
      bf16x8 bv8 = *(const bf16x8*)&s_v[(dt*16 + m)*136 + kc4*32 + quad*8];
      accn[dt] = __builtin_amdgcn_mfma_f32_16x16x32_bf16(a, bv8, accn[dt], 0,0,0);
    }
  }

  // ---- f_sum (strided entries) ----
  #pragma unroll
  for (int off=1; off<16; off<<=1)
    #pragma unroll
    for (int r=0;r<4;r++) fs[r] += __shfl_xor(fs[r], off, 64);
  if (m == 0){
    #pragma unroll
    for (int r=0;r<4;r++)
      atomicAdd(&f_sum[(b*64 + rowbase + quad*4 + r)*32], fs[r]);
  }
  // ---- know atomics -> replica ----
  float* kr = know + (size_t)(rep*2 + b)*4096;
  #pragma unroll
  for (int dt=0;dt<4;dt++)
    #pragma unroll
    for (int r=0;r<4;r++)
      atomicAdd(&kr[(rowbase + quad*4 + r)*64 + dt*16 + m], accn[dt][r]);
}

// ---------- mem update + Meff(bf16) + beff via MFMA; re-zero accumulators ----------
__global__ __launch_bounds__(256) void k_memupd_meff(
    float* __restrict__ know, float* __restrict__ f_sum,
    const float* __restrict__ hidden_in,
    const short* __restrict__ Wpb, const short* __restrict__ Wqtb,
    const float* __restrict__ bqP, const float* __restrict__ bpP,
    int l, float* __restrict__ hidden_out,
    short* __restrict__ Meffb, float* __restrict__ beff,
    float* __restrict__ ssum_next)
{
  int b = blockIdx.x;
  int t = threadIdx.x;
  int w = t >> 6;
  int lane = t & 63;
  int m = lane & 15;
  int quad = lane >> 4;

  __shared__ short s_memb[64*72];  // mem[c][d] bf16, stride 72
  __shared__ short s_mfb[64*72];   // mf[o][c] bf16, stride 72
  __shared__ float s_bq[64];

  if (t < 64) s_bq[t] = bqP[l*64 + t];

  const float invN = 1.0f/(float)NPIX;
  // ---- phase 1: mem = fmean*prev + know/N ----
  #pragma unroll
  for (int i=0;i<16;i++){
    int cd = t + i*256;
    int c = cd >> 6, d = cd & 63;
    float fmean = f_sum[(b*64 + c)*32] * invN;
    float kn = 0.f;
    #pragma unroll
    for (int rep=0; rep<4; rep++){
      kn += know[(size_t)(rep*2+b)*4096 + cd];
      know[(size_t)(rep*2+b)*4096 + cd] = 0.f;
    }
    kn *= invN;
    float pm = hidden_in[(size_t)(b*NLAYER+l)*4096 + cd];
    float nm = fmean*pm + kn;
    hidden_out[(size_t)(b*NLAYER+l)*4096 + cd] = nm;
    s_memb[c*72 + d] = f2bs(nm);
  }
  __syncthreads();
  if (t < 64) f_sum[(b*64 + t)*32] = 0.f;
  if (t < 16) ssum_next[(b*16 + t)*32] = 0.f;

  f32x4 z4 = {0.f,0.f,0.f,0.f};

  // ---- GEMM1: mf[o][c] = sum_d Wp[o][d]*mem[c][d]; wave w owns rows w*16..+15 ----
  bf16x8 Ap[2];
  #pragma unroll
  for (int kc=0;kc<2;kc++)
    Ap[kc] = *(const bf16x8*)&Wpb[l*4096 + (w*16+m)*64 + kc*32 + quad*8];

  float be[4];
  #pragma unroll
  for (int r=0;r<4;r++) be[r] = 0.f;

  #pragma unroll
  for (int ct=0; ct<4; ct++){
    f32x4 a = z4;
    #pragma unroll
    for (int kc=0;kc<2;kc++){
      bf16x8 Bm = *(const bf16x8*)&s_memb[(ct*16+m)*72 + kc*32 + quad*8];
      a = __builtin_amdgcn_mfma_f32_16x16x32_bf16(Ap[kc], Bm, a, 0,0,0);
    }
    int c = ct*16 + m;
    #pragma unroll
    for (int r=0;r<4;r++){
      int o = w*16 + quad*4 + r;
      s_mfb[o*72 + c] = f2bs(a[r]);
      be[r] += a[r] * s_bq[c];
    }
  }
  // beff: reduce over the 16 m-lanes (cols)
  #pragma unroll
  for (int off=1; off<16; off<<=1)
    #pragma unroll
    for (int r=0;r<4;r++) be[r] += __shfl_xor(be[r], off, 64);
  if (m == 0){
    #pragma unroll
    for (int r=0;r<4;r++){
      int o = w*16 + quad*4 + r;
      beff[b*64 + o] = bpP[l*64 + o] + 0.125f*be[r];
    }
  }
  __syncthreads();

  // ---- GEMM2: Meff[o][e] = 0.125 * sum_c mf[o][c]*WqT[e][c] ----
  bf16x8 Am2[2];
  #pragma unroll
  for (int kc=0;kc<2;kc++)
    Am2[kc] = *(const bf16x8*)&s_mfb[(w*16+m)*72 + kc*32 + quad*8];
  #pragma unroll
  for (int et=0; et<4; et++){
    f32x4 a = z4;
    #pragma unroll
    for (int kc=0;kc<2;kc++){
      bf16x8 Bq = *(const bf16x8*)&Wqtb[l*4096 + (et*16+m)*64 + kc*32 + quad*8];
      a = __builtin_amdgcn_mfma_f32_16x16x32_bf16(Am2[kc], Bq, a, 0,0,0);
    }
    #pragma unroll
    for (int r=0;r<4;r++){
      int o = w*16 + quad*4 + r;
      Meffb[(size_t)b*4096 + o*64 + et*16 + m] = f2bs(0.125f*a[r]);
    }
  }
}

// ---------- retrieval+proj+residual in-place + next-layer GN stats ----------
__global__ __launch_bounds__(256,3) void k_retrproj(
    const float* __restrict__ ssum_l,
    const float* __restrict__ gammaP, const float* __restrict__ betaP,
    const short* __restrict__ Meffb, const float* __restrict__ beff,
    int l, float* __restrict__ feat, float* __restrict__ ssum_next)
{
  int b = blockIdx.y;
  int n0 = blockIdx.x * 128;
  int t = threadIdx.x;
  int w = t >> 6;
  int lane = t & 63;
  int m = lane & 15;
  int quad = lane >> 4;

  __shared__ float s_out[128*68];   // 34816 B; aliased by s_xn during staging
  short* s_xn = (short*)s_out;      // [px][c] stride 72 (18432 B)
  __shared__ float s_gnA[64], s_gnB[64], s_beff[64];
  __shared__ float s_sacc[16];

  gnCoef(ssum_l, b, t, gammaP, betaP, l, s_gnA, s_gnB);
  if (t < 64) s_beff[t] = beff[b*64 + t];
  if (t < 16) s_sacc[t] = 0.f;
  __syncthreads();

  const float* fbase = feat + ((size_t)b*NPIX + n0)*64;
  #pragma unroll
  for (int i=0;i<8;i++){
    int chunk = t + i*256;
    int px = chunk >> 4, cq = chunk & 15;
    f32x4 fv = *(const f32x4*)(fbase + px*64 + cq*4);
    short4v xs;
    #pragma unroll
    for (int j=0;j<4;j++)
      xs[j] = f2bs(fmaf(fv[j], s_gnA[cq*4+j], s_gnB[cq*4+j]));
    *(short4v*)&s_xn[px*72 + cq*4] = xs;
  }
  __syncthreads();

  bf16x8 Bf[2][8];
  #pragma unroll
  for (int kc=0;kc<2;kc++)
    #pragma unroll
    for (int nt=0;nt<8;nt++)
      Bf[kc][nt] = *(const bf16x8*)&s_xn[(nt*16+m)*72 + kc*32 + quad*8];

  bf16x8 Am[2];
  #pragma unroll
  for (int kc=0;kc<2;kc++)
    Am[kc] = *(const bf16x8*)&Meffb[(size_t)b*4096 + (w*16 + m)*64 + kc*32 + quad*8];
  __syncthreads();   // s_xn dead; s_out writable

  f32x4 acc[8];
  f32x4 z4 = {0.f,0.f,0.f,0.f};
  #pragma unroll
  for (int nt=0;nt<8;nt++) acc[nt]=z4;
  #pragma unroll
  for (int kc=0;kc<2;kc++)
    #pragma unroll
    for (int nt=0;nt<8;nt++)
      acc[nt] = __builtin_amdgcn_mfma_f32_16x16x32_bf16(Am[kc], Bf[kc][nt], acc[nt], 0,0,0);

  // transpose retrieval output into [px][c]
  #pragma unroll
  for (int nt=0;nt<8;nt++)
    #pragma unroll
    for (int r=0;r<4;r++)
      s_out[(nt*16+m)*68 + w*16 + quad*4 + r] = acc[nt][r];
  __syncthreads();

  // writeback (feat re-read is L1-hot) + next-layer GN stats
  float gsv = 0.f, gqv = 0.f;
  int cq = t & 15;
  #pragma unroll
  for (int i=0;i<8;i++){
    int chunk = t + i*256;
    int px = chunk >> 4;
    float* fp = (float*)(fbase + px*64 + cq*4);
    f32x4 fv = *(const f32x4*)fp;
    f32x4 ov = *(const f32x4*)&s_out[px*68 + cq*4];
    f32x4 res;
    #pragma unroll
    for (int j=0;j<4;j++){
      float o = fv[j] + ov[j] + s_beff[cq*4+j];
      res[j] = o;
      gsv += o; gqv += o*o;
    }
    *(f32x4*)fp = res;
  }
  // reduce the 8 lanes sharing a group (xor bits 0,4,5)
  gsv += __shfl_xor(gsv, 1, 64);  gqv += __shfl_xor(gqv, 1, 64);
  gsv += __shfl_xor(gsv, 16, 64); gqv += __shfl_xor(gqv, 16, 64);
  gsv += __shfl_xor(gsv, 32, 64); gqv += __shfl_xor(gqv, 32, 64);
  if ((lane & 49) == 0){
    int g = (lane & 15) >> 1;
    atomicAdd(&s_sacc[g*2], gsv);
    atomicAdd(&s_sacc[g*2+1], gqv);
  }
  __syncthreads();
  if (t < 16) atomicAdd(&ssum_next[(b*16 + t)*32], s_sacc[t]);
}

// ---------- conv3x3 64->2 + residual; feat [px][c], weights [o][k][c] ----------
__global__ void k_conv_out(const float* __restrict__ feat, const float* __restrict__ wt,
                           const float* __restrict__ bias,
                           const float* __restrict__ xin, float* __restrict__ out){
  int b = blockIdx.y;
  int y = blockIdx.x;
  int xx = threadIdx.x;
  float acc0 = bias[0], acc1 = bias[1];
  #pragma unroll
  for (int dy=-1; dy<=1; dy++){
    int yy = y + dy;
    if (yy < 0 || yy >= HDIM) continue;
    #pragma unroll
    for (int dx=-1; dx<=1; dx++){
      int xc = xx + dx;
      if (xc >= 0 && xc < HDIM){
        const float* fp = feat + ((size_t)b*NPIX + yy*HDIM + xc)*64;
        const float* w0 = wt + ((0*3 + dy+1)*3 + dx+1)*64;
        const float* w1 = wt + ((1*3 + dy+1)*3 + dx+1)*64;
        #pragma unroll
        for (int c4=0;c4<16;c4++){
          f32x4 fv  = *(const f32x4*)(fp + c4*4);
          f32x4 wv0 = *(const f32x4*)(w0 + c4*4);
          f32x4 wv1 = *(const f32x4*)(w1 + c4*4);
          #pragma unroll
          for (int j=0;j<4;j++){
            acc0 += fv[j]*wv0[j];
            acc1 += fv[j]*wv1[j];
          }
        }
      }
    }
  }
  size_t p0 = (size_t)(b*2+0)*NPIX + y*HDIM + xx;
  size_t p1 = (size_t)(b*2+1)*NPIX + y*HDIM + xx;
  out[p0] = acc0 + xin[p0];
  out[p1] = acc1 + xin[p1];
}

extern "C" void kernel_launch(void* const* d_in, const int* in_sizes, int n_in,
                              void* d_out, int out_size, void* d_ws, size_t ws_size,
                              hipStream_t stream){
  char* ws = (char*)d_ws;
  float* feat  = (float*)(ws + OFS_FEAT);
  float* know  = (float*)(ws + OFS_KNOW);
  float* fsum  = (float*)(ws + OFS_FSUM);
  float* ssum  = (float*)(ws + OFS_SSUM);   // 2 ping buffers of 1024 floats
  float* beff  = (float*)(ws + OFS_BEFF);
  short* meffb = (short*)(ws + OFS_MEFFB);
  short* wkb   = (short*)(ws + OFS_WKB);
  short* wvb   = (short*)(ws + OFS_WVB);
  short* wgb   = (short*)(ws + OFS_WGB);
  float* wtout = (float*)(ws + OFS_WTOUT);
  short* wpb   = (short*)(ws + OFS_WPB);
  short* wqtb  = (short*)(ws + OFS_WQTB);

  const float* x      = (const float*)d_in[0];
  const float* hidden = (const float*)d_in[1];
  const float* W_in   = (const float*)d_in[2];
  const float* b_in   = (const float*)d_in[3];
  const float* gamma  = (const float*)d_in[4];
  const float* beta   = (const float*)d_in[5];
  const float* Wq     = (const float*)d_in[6];
  const float* bq     = (const float*)d_in[7];
  const float* Wk     = (const float*)d_in[8];
  const float* bk     = (const float*)d_in[9];
  const float* Wv     = (const float*)d_in[10];
  const float* bv     = (const float*)d_in[11];
  const float* Wg     = (const float*)d_in[12];
  const float* bg     = (const float*)d_in[13];
  const float* Wp     = (const float*)d_in[14];
  const float* bp     = (const float*)d_in[15];
  const float* W_out  = (const float*)d_in[16];
  const float* b_out  = (const float*)d_in[17];

  float* out        = (float*)d_out;
  float* hidden_out = out + BATCH*2*NPIX;

  hipMemsetAsync(ws + OFS_KNOW, 0, ZERO_BYTES, stream);
  k_prepw<<<dim3(128), dim3(256), 0, stream>>>(Wk, Wv, Wg, W_out, Wp, Wq,
                                               wkb, wvb, wgb, wtout, wpb, wqtb);
  k_conv_in<<<dim3(HDIM, BATCH), dim3(256), 0, stream>>>(x, W_in, b_in, feat, ssum);

  for (int l=0; l<NLAYER; l++){
    float* ssum_l = ssum + (l & 1)*1024;
    float* ssum_n = ssum + ((l+1) & 1)*1024;
    k_qkvg_know<<<dim3(NPIX/128, BATCH), dim3(256), 0, stream>>>(
        feat, ssum_l, gamma, beta, wkb, bk, wvb, bv, wgb, bg, l, know, fsum);
    k_memupd_meff<<<dim3(BATCH), dim3(256), 0, stream>>>(
        know, fsum, hidden, wpb, wqtb, bq, bp, l, hidden_out, meffb, beff, ssum_n);
    k_retrproj<<<dim3(NPIX/128, BATCH), dim3(256), 0, stream>>>(
        ssum_l, gamma, beta, meffb, beff, l, feat, ssum_n);
  }

  k_conv_out<<<dim3(HDIM, BATCH), dim3(256), 0, stream>>>(feat, wtout, b_out, x, out);
}